// Round 14
// baseline (923.490 us; speedup 1.0000x reference)
//
#include <hip/hip_runtime.h>
#include <hip/hip_bf16.h>

#define NN 50000   // nodes
#define NE 800000  // edges
#define DD 128     // node dim
#define HH 128     // hidden dim
#define RR 64      // num rbf
#define LL 4       // layers
#define GG 64      // graphs
#define EB 64      // edges per block (edge kernel)

typedef float f4 __attribute__((ext_vector_type(4)));
typedef __attribute__((ext_vector_type(8))) short bf16x8;  // MFMA A/B frag (4 VGPR)
typedef __attribute__((ext_vector_type(4))) float f32x4;   // MFMA C/D frag

// silu via hardware rcp (~1 ulp; way below bf16 quantum).
__device__ __forceinline__ float silu1(float v)
{
    return v * __builtin_amdgcn_rcpf(1.0f + __expf(-v));
}

// RNE float -> bf16 bits (branchless; inputs finite)
__device__ __forceinline__ unsigned short f2bf(float f)
{
    union { float f; unsigned u; } x; x.f = f;
    unsigned r = x.u + 0x7fffu + ((x.u >> 16) & 1u);
    return (unsigned short)(r >> 16);
}
__device__ __forceinline__ float bf2f(unsigned short h)
{
    union { unsigned u; float f; } x; x.u = ((unsigned)h) << 16; return x.f;
}
// Packed RNE pair convert via the OFFICIAL HIP API (round 12's hand asm had
// wrong semantics; this one is guaranteed: low16 = bf16(a), high16 = bf16(b)).
__device__ __forceinline__ unsigned pk2bf(float a, float b)
{
    __hip_bfloat162 h = __float22bfloat162_rn(float2{a, b});
    union { __hip_bfloat162 h; unsigned u; } c; c.h = h;
    return c.u;
}

// ---------------------------------------------------------------------------
// Zero fill
// ---------------------------------------------------------------------------
__global__ void fillz_kernel(float* __restrict__ p, int n4)
{
    int i = blockIdx.x * 256 + threadIdx.x;
    if (i < n4) ((f4*)p)[i] = (f4){0.f, 0.f, 0.f, 0.f};
}

// ---------------------------------------------------------------------------
// Counting sort of edges by col (destination). One-time per call.
// ---------------------------------------------------------------------------
__global__ void hist_kernel(const int* __restrict__ ecol, int* __restrict__ cnt)
{
    int e = blockIdx.x * 256 + threadIdx.x;
    if (e < NE) atomicAdd(&cnt[ecol[e]], 1);
}

__global__ void scan_kernel(const int* __restrict__ cnt, int* __restrict__ cur)
{
    __shared__ int s[1024];
    int t = threadIdx.x;               // 1024 threads, 1 block
    const int CH = 49;                 // 1024*49 = 50176 >= NN
    int a0 = t * CH, a1 = a0 + CH; if (a1 > NN) a1 = NN; if (a0 > NN) a0 = NN;
    int s0 = 0;
    for (int i = a0; i < a1; ++i) s0 += cnt[i];
    s[t] = s0;
    __syncthreads();
    for (int off = 1; off < 1024; off <<= 1) {
        int v = (t >= off) ? s[t - off] : 0;
        __syncthreads();
        s[t] += v;
        __syncthreads();
    }
    int base = (t == 0) ? 0 : s[t - 1];
    for (int i = a0; i < a1; ++i) { cur[i] = base; base += cnt[i]; }
}

__global__ void scatter_kernel(const float* __restrict__ pos,
                               const int* __restrict__ erow, const int* __restrict__ ecol,
                               int* __restrict__ cur,
                               int* __restrict__ srow, int* __restrict__ scol,
                               float* __restrict__ sdist)
{
    int e = blockIdx.x * 256 + threadIdx.x;
    if (e >= NE) return;
    int r = erow[e], c = ecol[e];
    int p = atomicAdd(&cur[c], 1);
    srow[p] = r;
    scol[p] = c;
    float dx = pos[r * 3 + 0] - pos[c * 3 + 0];
    float dy = pos[r * 3 + 1] - pos[c * 3 + 1];
    float dz = pos[r * 3 + 2] - pos[c * 3 + 2];
    sdist[p] = sqrtf(dx * dx + dy * dy + dz * dz);
}

// ---------------------------------------------------------------------------
// Graph segment boundaries from sorted batch
// ---------------------------------------------------------------------------
__global__ void gstart_kernel(const int* __restrict__ batch, int* __restrict__ gstart)
{
    int i = blockIdx.x * 256 + threadIdx.x;
    if (i >= NN) return;
    int b = batch[i];
    if (i == 0) {
        for (int g = 0; g <= b; ++g) gstart[g] = 0;
    } else {
        int bp = batch[i - 1];
        for (int g = bp + 1; g <= b; ++g) gstart[g] = i;
    }
    if (i == NN - 1) {
        for (int g = b + 1; g <= GG; ++g) gstart[g] = NN;
    }
}

// ---------------------------------------------------------------------------
// Weight folding (fp32), parallel: one thread per output element.
// ---------------------------------------------------------------------------
__global__ void fold_kernel(const float* __restrict__ Wnode, const float* __restrict__ Wrbf,
                            const float* __restrict__ We1,
                            const float* __restrict__ bnode, const float* __restrict__ brbf,
                            const float* __restrict__ be1,
                            float* __restrict__ Wpa, float* __restrict__ Wqb,
                            float* __restrict__ Wc, float* __restrict__ bmsg)
{
    int l = blockIdx.y;
    int o = blockIdx.x * 256 + threadIdx.x;
    const float* We1l = We1 + (size_t)l * 384 * 128;
    if (o < 16384) {
        int r = o >> 7, c = o & 127;
        const float* A = Wnode + (size_t)l * 16384;
        float s = 0.f;
        for (int k = 0; k < 128; ++k) s += A[r * 128 + k] * We1l[k * 128 + c];
        Wpa[(size_t)l * 16384 + o] = s;
    } else if (o < 32768) {
        int oo = o - 16384;
        int r = oo >> 7, c = oo & 127;
        const float* A = Wnode + (size_t)l * 16384;
        const float* B = We1l + 16384;
        float s = 0.f;
        for (int k = 0; k < 128; ++k) s += A[r * 128 + k] * B[k * 128 + c];
        Wqb[(size_t)l * 16384 + oo] = s;
    } else if (o < 40960) {
        int oo = o - 32768;
        int r = oo >> 7, c = oo & 127;
        const float* A = Wrbf + (size_t)l * 8192;
        const float* B = We1l + 32768;
        float s = 0.f;
        for (int k = 0; k < 128; ++k) s += A[r * 128 + k] * B[k * 128 + c];
        Wc[(size_t)l * 8192 + oo] = s;
    } else if (o < 41088) {
        int j = o - 40960;
        float s = be1[l * 128 + j];
        for (int k = 0; k < 128; ++k) {
            float w = We1l[k * 128 + j] + We1l[(128 + k) * 128 + j];
            s += bnode[l * 128 + k] * w + brbf[l * 128 + k] * We1l[(256 + k) * 128 + j];
        }
        bmsg[l * 128 + j] = s;
    }
}

// ---------------------------------------------------------------------------
// Pack fp32 weight M[K][128] into per-lane MFMA B-fragment order, bf16
// ---------------------------------------------------------------------------
__global__ void pack_kernel(const float* __restrict__ M, unsigned short* __restrict__ pk, int K)
{
    int idx = blockIdx.x * 256 + threadIdx.x;
    if (idx >= K * 128) return;
    int k = idx >> 7, c = idx & 127;
    int kc = k >> 5, hi = (k >> 3) & 3, j = k & 7;
    int cbG = c >> 4, lo = c & 15;
    int lane = hi * 16 + lo;
    pk[(((kc * 8 + cbG) * 64 + lane) * 8) + j] = f2bf(M[idx]);
}

// Same, but hi/lo split pair (for node-path weights: removes B-quant error)
__global__ void pack2_kernel(const float* __restrict__ M,
                             unsigned short* __restrict__ pkh,
                             unsigned short* __restrict__ pkl, int K)
{
    int idx = blockIdx.x * 256 + threadIdx.x;
    if (idx >= K * 128) return;
    int k = idx >> 7, c = idx & 127;
    int kc = k >> 5, hi = (k >> 3) & 3, j = k & 7;
    int cbG = c >> 4, lo = c & 15;
    int lane = hi * 16 + lo;
    int o = (((kc * 8 + cbG) * 64 + lane) * 8) + j;
    float v = M[idx];
    unsigned short h = f2bf(v);
    pkh[o] = h;
    pkl[o] = f2bf(v - bf2f(h));
}

// ---------------------------------------------------------------------------
// MFMA dual node GEMM, split-precision A AND B (3-term products):
//   P = X @ Wpa, Q = X @ Wqb; also zeroes agg rows.
// ---------------------------------------------------------------------------
__global__ __launch_bounds__(256, 2)
void nodepq_kernel(const float* __restrict__ X,
                   const unsigned short* __restrict__ pkpah,
                   const unsigned short* __restrict__ pkpal,
                   const unsigned short* __restrict__ pkqbh,
                   const unsigned short* __restrict__ pkqbl,
                   float* __restrict__ P, float* __restrict__ Q,
                   float* __restrict__ agg)
{
    __shared__ unsigned short s_h[64 * 128];  // 16 KB, swizzled (hi)
    __shared__ unsigned short s_l[64 * 128];  // 16 KB, swizzled (lo)

    const int tid = threadIdx.x;
    const int w = tid >> 6;
    const int lane = tid & 63;
    const int lo = lane & 15, hi = lane >> 4;
    const int r0 = blockIdx.x * 64;
    const int colbase = w * 32;

    for (int i = tid; i < 1024; i += 256) {
        int e = i >> 4, cg = i & 15;
        int r = r0 + e;
        union { unsigned short u16[8]; f4 v; } H, L;
        if (r < NN) {
            f4 v0 = ((const f4*)X)[(size_t)r * 32 + cg * 2];
            f4 v1 = ((const f4*)X)[(size_t)r * 32 + cg * 2 + 1];
#pragma unroll
            for (int q = 0; q < 4; ++q) {
                unsigned short h0 = f2bf(v0[q]);
                unsigned short h1 = f2bf(v1[q]);
                H.u16[q] = h0;     L.u16[q] = f2bf(v0[q] - bf2f(h0));
                H.u16[4 + q] = h1; L.u16[4 + q] = f2bf(v1[q] - bf2f(h1));
            }
        } else {
#pragma unroll
            for (int q = 0; q < 8; ++q) { H.u16[q] = 0; L.u16[q] = 0; }
        }
        int byte = e * 256 + ((cg * 16) ^ ((e & 7) << 4));
        *reinterpret_cast<f4*>((char*)s_h + byte) = H.v;
        *reinterpret_cast<f4*>((char*)s_l + byte) = L.v;
    }
    for (int i = tid; i < 2048; i += 256) {
        int e = i >> 5, cc = i & 31;
        int r = r0 + e;
        if (r < NN) ((f4*)agg)[(size_t)r * 32 + cc] = (f4){0.f, 0.f, 0.f, 0.f};
    }
    __syncthreads();

    f32x4 accp[4][2], accq[4][2];
#pragma unroll
    for (int rb = 0; rb < 4; ++rb)
#pragma unroll
        for (int cb = 0; cb < 2; ++cb) {
            accp[rb][cb] = (f32x4){0.f, 0.f, 0.f, 0.f};
            accq[rb][cb] = (f32x4){0.f, 0.f, 0.f, 0.f};
        }

#pragma unroll
    for (int kc = 0; kc < 4; ++kc) {
        bf16x8 ah[4], al[4];
#pragma unroll
        for (int rb = 0; rb < 4; ++rb) {
            int row = rb * 16 + lo;
            int byte = row * 256 + ((kc * 64 + hi * 16) ^ ((row & 7) << 4));
            ah[rb] = *reinterpret_cast<const bf16x8*>((const char*)s_h + byte);
            al[rb] = *reinterpret_cast<const bf16x8*>((const char*)s_l + byte);
        }
#pragma unroll
        for (int cb = 0; cb < 2; ++cb) {
            size_t boff = ((size_t)((kc * 8 + w * 2 + cb) * 64 + lane)) * 8;
            bf16x8 bph = *reinterpret_cast<const bf16x8*>(pkpah + boff);
            bf16x8 bpl = *reinterpret_cast<const bf16x8*>(pkpal + boff);
            bf16x8 bqh = *reinterpret_cast<const bf16x8*>(pkqbh + boff);
            bf16x8 bql = *reinterpret_cast<const bf16x8*>(pkqbl + boff);
#pragma unroll
            for (int rb = 0; rb < 4; ++rb) {
                accp[rb][cb] = __builtin_amdgcn_mfma_f32_16x16x32_bf16(ah[rb], bph, accp[rb][cb], 0, 0, 0);
                accp[rb][cb] = __builtin_amdgcn_mfma_f32_16x16x32_bf16(al[rb], bph, accp[rb][cb], 0, 0, 0);
                accp[rb][cb] = __builtin_amdgcn_mfma_f32_16x16x32_bf16(ah[rb], bpl, accp[rb][cb], 0, 0, 0);
                accq[rb][cb] = __builtin_amdgcn_mfma_f32_16x16x32_bf16(ah[rb], bqh, accq[rb][cb], 0, 0, 0);
                accq[rb][cb] = __builtin_amdgcn_mfma_f32_16x16x32_bf16(al[rb], bqh, accq[rb][cb], 0, 0, 0);
                accq[rb][cb] = __builtin_amdgcn_mfma_f32_16x16x32_bf16(ah[rb], bql, accq[rb][cb], 0, 0, 0);
            }
        }
    }

#pragma unroll
    for (int rb = 0; rb < 4; ++rb)
#pragma unroll
        for (int r = 0; r < 4; ++r) {
            int row = r0 + rb * 16 + hi * 4 + r;
            if (row < NN) {
#pragma unroll
                for (int cb = 0; cb < 2; ++cb) {
                    int col = colbase + cb * 16 + lo;
                    P[(size_t)row * 128 + col] = accp[rb][cb][r];
                    Q[(size_t)row * 128 + col] = accq[rb][cb][r];
                }
            }
        }
}

// ---------------------------------------------------------------------------
// MFMA edge kernel: wave w owns 16 edges [16w,16w+16) x ALL 128 cols.
// Round 14: f2bf -> official __float22bfloat162_rn packed converts (cuts the
// ~320 VALU-inst/thread manual-rounding block roughly in half of total VALU).
// ---------------------------------------------------------------------------
__global__ __launch_bounds__(256, 4)
void edge_mfma_kernel(const float* __restrict__ P, const float* __restrict__ Q,
                      const float* __restrict__ sdist,
                      const int* __restrict__ srow, const int* __restrict__ scol,
                      const unsigned short* __restrict__ pk1,  // [2][8][64][8]
                      const unsigned short* __restrict__ pk3,  // [4][8][64][8]
                      const float* __restrict__ bmsg, const float* __restrict__ be2,
                      float* __restrict__ agg)
{
    __shared__ unsigned short s_t[EB * 128];  // 16 KB, swizzled (C1 then t, in place)
    __shared__ float s_d[EB];
    __shared__ int s_row[EB], s_col[EB];
    __shared__ int s_rs[EB + 1];
    __shared__ int s_nr;

    const int tid = threadIdx.x;
    const int w = tid >> 6;
    const int lane = tid & 63;
    const int lo = lane & 15, hi = lane >> 4;
    const int e0 = blockIdx.x * EB;
    const int ew = w * 16;                    // wave's edge window [ew, ew+16)

    if (tid < EB) {
        s_d[tid] = sdist[e0 + tid];
        s_row[tid] = srow[e0 + tid];
        s_col[tid] = scol[e0 + tid];
    }
    __syncthreads();

    if (w == 0) {
        int c = s_col[lane];
        bool flag = (lane == 0) || (c != s_col[lane - 1]);
        unsigned long long m = __ballot(flag);
        if (flag) {
            int rank = __popcll(m & ((1ull << lane) - 1ull));
            s_rs[rank] = lane;
        }
        if (lane == 0) {
            int nr = __popcll(m);
            s_nr = nr;
            s_rs[nr] = EB;
        }
    }
    // (s_rs/s_nr visibility guaranteed by the barriers before phase 4)

    // ---- phase 1: C1 = RBF @ Wc  (K = 64); A row = local edge = lo
    f32x4 acc[8];
#pragma unroll
    for (int cb = 0; cb < 8; ++cb) acc[cb] = (f32x4){0.f, 0.f, 0.f, 0.f};

    const float dvv = s_d[ew + lo];
    const float step = 6.0f / 63.0f;
#pragma unroll
    for (int kc = 0; kc < 2; ++kc) {
        union { bf16x8 v; unsigned u32[4]; } U;
#pragma unroll
        for (int j2 = 0; j2 < 4; ++j2) {
            float t0 = dvv - (float)(kc * 32 + hi * 8 + 2 * j2) * step;
            float t1 = dvv - (float)(kc * 32 + hi * 8 + 2 * j2 + 1) * step;
            U.u32[j2] = pk2bf(__expf(-10.0f * t0 * t0), __expf(-10.0f * t1 * t1));
        }
#pragma unroll
        for (int cb = 0; cb < 8; ++cb) {
            bf16x8 b = *reinterpret_cast<const bf16x8*>(
                pk1 + ((size_t)((kc * 8 + cb) * 64 + lane)) * 8);
            acc[cb] = __builtin_amdgcn_mfma_f32_16x16x32_bf16(U.v, b, acc[cb], 0, 0, 0);
        }
    }

    // ---- phase 2a: dump C1 (bf16, packed converts) into s_t at final slots
#pragma unroll
    for (int r = 0; r < 4; ++r) {
        int e = ew + hi * 4 + r;
        int sw = (e & 7) << 4;
#pragma unroll
        for (int cb = 0; cb < 8; cb += 2) {
            unsigned pk = pk2bf(acc[cb][r], acc[cb + 1][r]);
            int c0 = cb * 16 + lo, c1 = c0 + 16;
            *(unsigned short*)((char*)s_t + e * 256 + ((c0 * 2) ^ sw)) = (unsigned short)pk;
            *(unsigned short*)((char*)s_t + e * 256 + ((c1 * 2) ^ sw)) = (unsigned short)(pk >> 16);
        }
    }
    __syncthreads();

    // ---- phase 2b: coalesced f4 gather of P,Q; v = C1+P+Q+bm; t = silu(v),
    //      written back in place (each 8B slot owned by exactly one thread).
    {
        const int f4c = tid & 31;           // f4-col (cols 4*f4c .. 4*f4c+3)
        const int ebase = (tid >> 5) * 8;   // 8 edges per 32-thread group
        f4 bmv = ((const f4*)bmsg)[f4c];
#pragma unroll
        for (int p = 0; p < 8; ++p) {
            int e = ebase + p;
            int nc = s_col[e], nr = s_row[e];
            f4 pv = ((const f4*)(P + (size_t)nc * 128))[f4c];
            f4 qv = ((const f4*)(Q + (size_t)nr * 128))[f4c];
            int byte = e * 256 + ((f4c * 8) ^ ((e & 7) << 4));
            unsigned long long c1 = *(unsigned long long*)((char*)s_t + byte);
            float t[4];
#pragma unroll
            for (int j = 0; j < 4; ++j) {
                float c1f = bf2f((unsigned short)(c1 >> (16 * j)));
                t[j] = silu1(c1f + pv[j] + qv[j] + bmv[j]);
            }
            unsigned lo32 = pk2bf(t[0], t[1]);
            unsigned hi32 = pk2bf(t[2], t[3]);
            *(unsigned long long*)((char*)s_t + byte) =
                (unsigned long long)lo32 | ((unsigned long long)hi32 << 32);
        }
    }
    __syncthreads();

    // ---- phase 3: M = T @ We2  (K = 128); A row = ew + lo
    f32x4 acc2[8];
#pragma unroll
    for (int cb = 0; cb < 8; ++cb) acc2[cb] = (f32x4){0.f, 0.f, 0.f, 0.f};

    {
        const int rowA = ew + lo;
        const int swA = (rowA & 7) << 4;
#pragma unroll
        for (int kc = 0; kc < 4; ++kc) {
            bf16x8 a = *reinterpret_cast<const bf16x8*>(
                (const char*)s_t + rowA * 256 + ((kc * 64 + hi * 16) ^ swA));
#pragma unroll
            for (int cb = 0; cb < 8; ++cb) {
                bf16x8 b = *reinterpret_cast<const bf16x8*>(
                    pk3 + ((size_t)((kc * 8 + cb) * 64 + lane)) * 8);
                acc2[cb] = __builtin_amdgcn_mfma_f32_16x16x32_bf16(a, b, acc2[cb], 0, 0, 0);
            }
        }
    }

    // ---- phase 4: per-run reduce clipped to this wave's window + atomicAdd
    float be2c[8];
#pragma unroll
    for (int cb = 0; cb < 8; ++cb) be2c[cb] = be2[cb * 16 + lo];

    int nruns = s_nr;
    for (int ri = 0; ri < nruns; ++ri) {
        int a0 = s_rs[ri], b0 = s_rs[ri + 1];
        if (b0 <= ew || a0 >= ew + 16) continue;   // wave-uniform skip
        int la = a0 - ew; if (la < 0) la = 0;
        int lb = b0 - ew; if (lb > 16) lb = 16;
        int node = s_col[a0];
        float s[8];
#pragma unroll
        for (int cb = 0; cb < 8; ++cb) s[cb] = 0.f;
#pragma unroll
        for (int r = 0; r < 4; ++r) {
            int el = hi * 4 + r;
            bool in = (el >= la) && (el < lb);
#pragma unroll
            for (int cb = 0; cb < 8; ++cb)
                s[cb] += in ? acc2[cb][r] : 0.f;
        }
#pragma unroll
        for (int cb = 0; cb < 8; ++cb) {
            s[cb] += __shfl_xor(s[cb], 16, 64);
            s[cb] += __shfl_xor(s[cb], 32, 64);
        }
        if (hi == 0) {
            float len = (float)(lb - la);
            float* dst = agg + (size_t)node * 128;
#pragma unroll
            for (int cb = 0; cb < 8; ++cb)
                atomicAdd(dst + cb * 16 + lo, s[cb] + len * be2c[cb]);
        }
    }
}

// ---------------------------------------------------------------------------
// MFMA node update, split-precision A AND B (3-term), both stages:
//   X_out = silu(agg @ W_u1 + b_u1) @ W_u2 + b_u2
// ---------------------------------------------------------------------------
__global__ __launch_bounds__(256, 2)
void nodeupd_kernel(const float* __restrict__ AGG,
                    const unsigned short* __restrict__ pku1h,
                    const unsigned short* __restrict__ pku1l,
                    const float* __restrict__ bu1,
                    const unsigned short* __restrict__ pku2h,
                    const unsigned short* __restrict__ pku2l,
                    const float* __restrict__ bu2,
                    float* __restrict__ Xout)
{
    __shared__ unsigned short s_h[64 * 128];  // 16 KB, swizzled (hi)
    __shared__ unsigned short s_l[64 * 128];  // 16 KB, swizzled (lo)

    const int tid = threadIdx.x;
    const int w = tid >> 6;
    const int lane = tid & 63;
    const int lo = lane & 15, hi = lane >> 4;
    const int r0 = blockIdx.x * 64;
    const int colbase = w * 32;

    for (int i = tid; i < 1024; i += 256) {
        int e = i >> 4, cg = i & 15;
        int r = r0 + e;
        union { unsigned short u16[8]; f4 v; } H, L;
        if (r < NN) {
            f4 v0 = ((const f4*)AGG)[(size_t)r * 32 + cg * 2];
            f4 v1 = ((const f4*)AGG)[(size_t)r * 32 + cg * 2 + 1];
#pragma unroll
            for (int q = 0; q < 4; ++q) {
                unsigned short h0 = f2bf(v0[q]);
                unsigned short h1 = f2bf(v1[q]);
                H.u16[q] = h0;     L.u16[q] = f2bf(v0[q] - bf2f(h0));
                H.u16[4 + q] = h1; L.u16[4 + q] = f2bf(v1[q] - bf2f(h1));
            }
        } else {
#pragma unroll
            for (int q = 0; q < 8; ++q) { H.u16[q] = 0; L.u16[q] = 0; }
        }
        int byte = e * 256 + ((cg * 16) ^ ((e & 7) << 4));
        *reinterpret_cast<f4*>((char*)s_h + byte) = H.v;
        *reinterpret_cast<f4*>((char*)s_l + byte) = L.v;
    }
    __syncthreads();

    // ---- stage 1: t = silu(agg @ Wu1 + b1)
    f32x4 acc[4][2];
#pragma unroll
    for (int rb = 0; rb < 4; ++rb)
#pragma unroll
        for (int cb = 0; cb < 2; ++cb) acc[rb][cb] = (f32x4){0.f, 0.f, 0.f, 0.f};

#pragma unroll
    for (int kc = 0; kc < 4; ++kc) {
        bf16x8 ah[4], al[4];
#pragma unroll
        for (int rb = 0; rb < 4; ++rb) {
            int row = rb * 16 + lo;
            int byte = row * 256 + ((kc * 64 + hi * 16) ^ ((row & 7) << 4));
            ah[rb] = *reinterpret_cast<const bf16x8*>((const char*)s_h + byte);
            al[rb] = *reinterpret_cast<const bf16x8*>((const char*)s_l + byte);
        }
#pragma unroll
        for (int cb = 0; cb < 2; ++cb) {
            size_t boff = ((size_t)((kc * 8 + w * 2 + cb) * 64 + lane)) * 8;
            bf16x8 bh = *reinterpret_cast<const bf16x8*>(pku1h + boff);
            bf16x8 bl = *reinterpret_cast<const bf16x8*>(pku1l + boff);
#pragma unroll
            for (int rb = 0; rb < 4; ++rb) {
                acc[rb][cb] = __builtin_amdgcn_mfma_f32_16x16x32_bf16(ah[rb], bh, acc[rb][cb], 0, 0, 0);
                acc[rb][cb] = __builtin_amdgcn_mfma_f32_16x16x32_bf16(al[rb], bh, acc[rb][cb], 0, 0, 0);
                acc[rb][cb] = __builtin_amdgcn_mfma_f32_16x16x32_bf16(ah[rb], bl, acc[rb][cb], 0, 0, 0);
            }
        }
    }

    float b1c[2];
#pragma unroll
    for (int cb = 0; cb < 2; ++cb) b1c[cb] = bu1[colbase + cb * 16 + lo];

    __syncthreads();  // all stage-1 LDS reads complete before overwrite

#pragma unroll
    for (int rb = 0; rb < 4; ++rb)
#pragma unroll
        for (int r = 0; r < 4; ++r) {
            int row = rb * 16 + hi * 4 + r;
#pragma unroll
            for (int cb = 0; cb < 2; ++cb) {
                int col = colbase + cb * 16 + lo;
                float t = silu1(acc[rb][cb][r] + b1c[cb]);
                unsigned short th = f2bf(t);
                unsigned short tl = f2bf(t - bf2f(th));
                int byte = row * 256 + ((col * 2) ^ ((row & 7) << 4));
                *(unsigned short*)((char*)s_h + byte) = th;
                *(unsigned short*)((char*)s_l + byte) = tl;
            }
        }
    __syncthreads();

    // ---- stage 2: X_out = t @ Wu2 + b2
    f32x4 acc2[4][2];
#pragma unroll
    for (int rb = 0; rb < 4; ++rb)
#pragma unroll
        for (int cb = 0; cb < 2; ++cb) acc2[rb][cb] = (f32x4){0.f, 0.f, 0.f, 0.f};

#pragma unroll
    for (int kc = 0; kc < 4; ++kc) {
        bf16x8 ah[4], al[4];
#pragma unroll
        for (int rb = 0; rb < 4; ++rb) {
            int row = rb * 16 + lo;
            int byte = row * 256 + ((kc * 64 + hi * 16) ^ ((row & 7) << 4));
            ah[rb] = *reinterpret_cast<const bf16x8*>((const char*)s_h + byte);
            al[rb] = *reinterpret_cast<const bf16x8*>((const char*)s_l + byte);
        }
#pragma unroll
        for (int cb = 0; cb < 2; ++cb) {
            size_t boff = ((size_t)((kc * 8 + w * 2 + cb) * 64 + lane)) * 8;
            bf16x8 bh = *reinterpret_cast<const bf16x8*>(pku2h + boff);
            bf16x8 bl = *reinterpret_cast<const bf16x8*>(pku2l + boff);
#pragma unroll
            for (int rb = 0; rb < 4; ++rb) {
                acc2[rb][cb] = __builtin_amdgcn_mfma_f32_16x16x32_bf16(ah[rb], bh, acc2[rb][cb], 0, 0, 0);
                acc2[rb][cb] = __builtin_amdgcn_mfma_f32_16x16x32_bf16(al[rb], bh, acc2[rb][cb], 0, 0, 0);
                acc2[rb][cb] = __builtin_amdgcn_mfma_f32_16x16x32_bf16(ah[rb], bl, acc2[rb][cb], 0, 0, 0);
            }
        }
    }

    float b2c[2];
#pragma unroll
    for (int cb = 0; cb < 2; ++cb) b2c[cb] = bu2[colbase + cb * 16 + lo];

#pragma unroll
    for (int rb = 0; rb < 4; ++rb)
#pragma unroll
        for (int r = 0; r < 4; ++r) {
            int row = r0 + rb * 16 + hi * 4 + r;
            if (row < NN) {
#pragma unroll
                for (int cb = 0; cb < 2; ++cb) {
                    int col = colbase + cb * 16 + lo;
                    Xout[(size_t)row * 128 + col] = acc2[rb][cb][r] + b2c[cb];
                }
            }
        }
}

// ---------------------------------------------------------------------------
// Graph readout: grid (G, 4); block reduces 32 cols of one graph segment
// ---------------------------------------------------------------------------
__global__ void gsum2_kernel(const float* __restrict__ X, const int* __restrict__ gstart,
                             float* __restrict__ Gm)
{
    __shared__ f4 red[32][8];
    int g = blockIdx.x;
    int q = blockIdx.y;
    int cq = threadIdx.x & 7;
    int cf = q * 8 + cq;          // f4 col (0..31)
    int rg = threadIdx.x >> 3;    // 0..31
    int i0 = gstart[g], i1 = gstart[g + 1];
    f4 s = {0.f, 0.f, 0.f, 0.f};
    for (int i = i0 + rg; i < i1; i += 32)
        s += ((const f4*)X)[(size_t)i * 32 + cf];
    red[rg][cq] = s;
    __syncthreads();
    for (int off = 16; off >= 1; off >>= 1) {
        if (rg < off) red[rg][cq] += red[rg + off][cq];
        __syncthreads();
    }
    if (rg == 0) ((f4*)Gm)[g * 32 + cf] = red[0][cq];
}

__global__ void final_kernel(const float* __restrict__ Gm,
                             const float* __restrict__ Wf1, const float* __restrict__ bf1,
                             const float* __restrict__ Wf2, const float* __restrict__ bf2,
                             float* __restrict__ out)
{
    __shared__ float red[128];
    int g = blockIdx.x;
    int j = threadIdx.x;
    float s = bf1[j];
    for (int k = 0; k < 128; ++k) s += Gm[(size_t)g * 128 + k] * Wf1[k * 128 + j];
    s = silu1(s);
    red[j] = s * Wf2[j];
    __syncthreads();
    for (int off = 64; off > 0; off >>= 1) {
        if (j < off) red[j] += red[j + off];
        __syncthreads();
    }
    if (j == 0) out[g] = red[0] + bf2[0];
}

// ---------------------------------------------------------------------------
extern "C" void kernel_launch(void* const* d_in, const int* in_sizes, int n_in,
                              void* d_out, int out_size, void* d_ws, size_t ws_size,
                              hipStream_t stream)
{
    const float* x     = (const float*)d_in[0];
    const float* pos   = (const float*)d_in[1];
    const int*   eidx  = (const int*)d_in[2];
    const int*   batch = (const int*)d_in[3];
    const float* Wnode = (const float*)d_in[4];
    const float* bnode = (const float*)d_in[5];
    const float* Wrbf  = (const float*)d_in[6];
    const float* brbf  = (const float*)d_in[7];
    const float* We1   = (const float*)d_in[8];
    const float* be1   = (const float*)d_in[9];
    const float* We2   = (const float*)d_in[10];
    const float* be2   = (const float*)d_in[11];
    const float* Wu1   = (const float*)d_in[12];
    const float* bu1   = (const float*)d_in[13];
    const float* Wu2   = (const float*)d_in[14];
    const float* bu2   = (const float*)d_in[15];
    const float* Wf1   = (const float*)d_in[16];
    const float* bf1   = (const float*)d_in[17];
    const float* Wf2   = (const float*)d_in[18];
    const float* bf2   = (const float*)d_in[19];

    const int* erow = eidx;
    const int* ecol = eidx + NE;

    char* wsb = (char*)d_ws;
    size_t off = 0;
    auto take = [&](size_t bytes) -> char* {
        char* p = wsb + off;
        off += (bytes + 255) & ~(size_t)255;
        return p;
    };
    float* Pb    = (float*)take((size_t)NN * HH * 4);
    float* Qb    = (float*)take((size_t)NN * HH * 4);
    float* aggb  = (float*)take((size_t)NN * HH * 4);
    float* xa    = (float*)take((size_t)NN * DD * 4);
    float* gm    = (float*)take((size_t)GG * DD * 4);
    float* Wpa   = (float*)take((size_t)LL * DD * HH * 4);
    float* Wqb   = (float*)take((size_t)LL * DD * HH * 4);
    float* Wcc   = (float*)take((size_t)LL * RR * HH * 4);
    float* bmsg  = (float*)take((size_t)LL * HH * 4);
    int*   cnt   = (int*)take((size_t)NN * 4);
    int*   cur   = (int*)take((size_t)NN * 4);
    int*   srow  = (int*)take((size_t)NE * 4);
    int*   scol  = (int*)take((size_t)NE * 4);
    float* sdist = (float*)take((size_t)NE * 4);
    int*   gst   = (int*)take((size_t)(GG + 1) * 4);
    unsigned short* pk1   = (unsigned short*)take((size_t)LL * RR * HH * 2);
    unsigned short* pk3   = (unsigned short*)take((size_t)LL * HH * HH * 2);
    unsigned short* pkpah = (unsigned short*)take((size_t)LL * DD * HH * 2);
    unsigned short* pkpal = (unsigned short*)take((size_t)LL * DD * HH * 2);
    unsigned short* pkqbh = (unsigned short*)take((size_t)LL * DD * HH * 2);
    unsigned short* pkqbl = (unsigned short*)take((size_t)LL * DD * HH * 2);
    unsigned short* pku1h = (unsigned short*)take((size_t)LL * HH * HH * 2);
    unsigned short* pku1l = (unsigned short*)take((size_t)LL * HH * HH * 2);
    unsigned short* pku2h = (unsigned short*)take((size_t)LL * HH * DD * 2);
    unsigned short* pku2l = (unsigned short*)take((size_t)LL * HH * DD * 2);

    if (off > ws_size) return;  // fail loudly (absmax), not a fault

    // ---- one-time preprocessing
    fillz_kernel<<<(NN + 1023) / 1024, 256, 0, stream>>>((float*)cnt, NN / 4);
    hist_kernel<<<(NE + 255) / 256, 256, 0, stream>>>(ecol, cnt);
    scan_kernel<<<1, 1024, 0, stream>>>(cnt, cur);
    scatter_kernel<<<(NE + 255) / 256, 256, 0, stream>>>(pos, erow, ecol, cur, srow, scol, sdist);
    gstart_kernel<<<(NN + 255) / 256, 256, 0, stream>>>(batch, gst);

    dim3 foldgrid((41088 + 255) / 256, LL);
    fold_kernel<<<foldgrid, 256, 0, stream>>>(Wnode, Wrbf, We1, bnode, brbf, be1,
                                              Wpa, Wqb, Wcc, bmsg);
    for (int l = 0; l < LL; ++l) {
        pack_kernel<<<(RR * HH + 255) / 256, 256, 0, stream>>>(
            Wcc + (size_t)l * RR * HH, pk1 + (size_t)l * RR * HH, RR);
        pack_kernel<<<(HH * HH + 255) / 256, 256, 0, stream>>>(
            We2 + (size_t)l * HH * HH, pk3 + (size_t)l * HH * HH, HH);
        pack2_kernel<<<(DD * HH + 255) / 256, 256, 0, stream>>>(
            Wpa + (size_t)l * DD * HH, pkpah + (size_t)l * DD * HH,
            pkpal + (size_t)l * DD * HH, DD);
        pack2_kernel<<<(DD * HH + 255) / 256, 256, 0, stream>>>(
            Wqb + (size_t)l * DD * HH, pkqbh + (size_t)l * DD * HH,
            pkqbl + (size_t)l * DD * HH, DD);
        pack2_kernel<<<(HH * HH + 255) / 256, 256, 0, stream>>>(
            Wu1 + (size_t)l * HH * HH, pku1h + (size_t)l * HH * HH,
            pku1l + (size_t)l * HH * HH, HH);
        pack2_kernel<<<(HH * DD + 255) / 256, 256, 0, stream>>>(
            Wu2 + (size_t)l * HH * DD, pku2h + (size_t)l * HH * DD,
            pku2l + (size_t)l * HH * DD, HH);
    }

    // ---- layers
    const int nblk = (NN + 63) / 64;
    const float* xin = x;
    for (int l = 0; l < LL; ++l) {
        nodepq_kernel<<<nblk, 256, 0, stream>>>(xin,
                                                pkpah + (size_t)l * DD * HH,
                                                pkpal + (size_t)l * DD * HH,
                                                pkqbh + (size_t)l * DD * HH,
                                                pkqbl + (size_t)l * DD * HH,
                                                Pb, Qb, aggb);
        edge_mfma_kernel<<<NE / EB, 256, 0, stream>>>(Pb, Qb, sdist, srow, scol,
                                                      pk1 + (size_t)l * RR * HH,
                                                      pk3 + (size_t)l * HH * HH,
                                                      bmsg + (size_t)l * HH,
                                                      be2 + (size_t)l * HH, aggb);
        nodeupd_kernel<<<nblk, 256, 0, stream>>>(aggb,
                                                 pku1h + (size_t)l * HH * HH,
                                                 pku1l + (size_t)l * HH * HH,
                                                 bu1 + (size_t)l * HH,
                                                 pku2h + (size_t)l * HH * DD,
                                                 pku2l + (size_t)l * HH * DD,
                                                 bu2 + (size_t)l * DD, xa);
        xin = xa;
    }

    dim3 gsgrid(GG, 4);
    gsum2_kernel<<<gsgrid, 256, 0, stream>>>(xin, gst, gm);
    final_kernel<<<GG, 128, 0, stream>>>(gm, Wf1, bf1, Wf2, bf2, (float*)d_out);
}

// Round 15
// 914.750 us; speedup vs baseline: 1.0096x; 1.0096x over previous
//
#include <hip/hip_runtime.h>
#include <hip/hip_bf16.h>

#define NN 50000   // nodes
#define NE 800000  // edges
#define DD 128     // node dim
#define HH 128     // hidden dim
#define RR 64      // num rbf
#define LL 4       // layers
#define GG 64      // graphs
#define EB 64      // edges per block (edge kernel)

typedef float f4 __attribute__((ext_vector_type(4)));
typedef __attribute__((ext_vector_type(8))) short bf16x8;  // MFMA A/B frag (4 VGPR)
typedef __attribute__((ext_vector_type(4))) float f32x4;   // MFMA C/D frag

// silu via hardware rcp (~1 ulp; way below bf16 quantum).
__device__ __forceinline__ float silu1(float v)
{
    return v * __builtin_amdgcn_rcpf(1.0f + __expf(-v));
}

// RNE float -> bf16 bits (branchless; inputs finite)
__device__ __forceinline__ unsigned short f2bf(float f)
{
    union { float f; unsigned u; } x; x.f = f;
    unsigned r = x.u + 0x7fffu + ((x.u >> 16) & 1u);
    return (unsigned short)(r >> 16);
}
__device__ __forceinline__ float bf2f(unsigned short h)
{
    union { unsigned u; float f; } x; x.u = ((unsigned)h) << 16; return x.f;
}
// Packed RNE pair convert via the official HIP API
__device__ __forceinline__ unsigned pk2bf(float a, float b)
{
    __hip_bfloat162 h = __float22bfloat162_rn(float2{a, b});
    union { __hip_bfloat162 h; unsigned u; } c; c.h = h;
    return c.u;
}

// ---------------------------------------------------------------------------
// Zero fill
// ---------------------------------------------------------------------------
__global__ void fillz_kernel(float* __restrict__ p, int n4)
{
    int i = blockIdx.x * 256 + threadIdx.x;
    if (i < n4) ((f4*)p)[i] = (f4){0.f, 0.f, 0.f, 0.f};
}

// ---------------------------------------------------------------------------
// Counting sort of edges by col (destination). One-time per call.
// ---------------------------------------------------------------------------
__global__ void hist_kernel(const int* __restrict__ ecol, int* __restrict__ cnt)
{
    int e = blockIdx.x * 256 + threadIdx.x;
    if (e < NE) atomicAdd(&cnt[ecol[e]], 1);
}

__global__ void scan_kernel(const int* __restrict__ cnt, int* __restrict__ cur)
{
    __shared__ int s[1024];
    int t = threadIdx.x;               // 1024 threads, 1 block
    const int CH = 49;                 // 1024*49 = 50176 >= NN
    int a0 = t * CH, a1 = a0 + CH; if (a1 > NN) a1 = NN; if (a0 > NN) a0 = NN;
    int s0 = 0;
    for (int i = a0; i < a1; ++i) s0 += cnt[i];
    s[t] = s0;
    __syncthreads();
    for (int off = 1; off < 1024; off <<= 1) {
        int v = (t >= off) ? s[t - off] : 0;
        __syncthreads();
        s[t] += v;
        __syncthreads();
    }
    int base = (t == 0) ? 0 : s[t - 1];
    for (int i = a0; i < a1; ++i) { cur[i] = base; base += cnt[i]; }
}

__global__ void scatter_kernel(const float* __restrict__ pos,
                               const int* __restrict__ erow, const int* __restrict__ ecol,
                               int* __restrict__ cur,
                               int* __restrict__ srow, int* __restrict__ scol,
                               float* __restrict__ sdist)
{
    int e = blockIdx.x * 256 + threadIdx.x;
    if (e >= NE) return;
    int r = erow[e], c = ecol[e];
    int p = atomicAdd(&cur[c], 1);
    srow[p] = r;
    scol[p] = c;
    float dx = pos[r * 3 + 0] - pos[c * 3 + 0];
    float dy = pos[r * 3 + 1] - pos[c * 3 + 1];
    float dz = pos[r * 3 + 2] - pos[c * 3 + 2];
    sdist[p] = sqrtf(dx * dx + dy * dy + dz * dz);
}

// ---------------------------------------------------------------------------
// Graph segment boundaries from sorted batch
// ---------------------------------------------------------------------------
__global__ void gstart_kernel(const int* __restrict__ batch, int* __restrict__ gstart)
{
    int i = blockIdx.x * 256 + threadIdx.x;
    if (i >= NN) return;
    int b = batch[i];
    if (i == 0) {
        for (int g = 0; g <= b; ++g) gstart[g] = 0;
    } else {
        int bp = batch[i - 1];
        for (int g = bp + 1; g <= b; ++g) gstart[g] = i;
    }
    if (i == NN - 1) {
        for (int g = b + 1; g <= GG; ++g) gstart[g] = NN;
    }
}

// ---------------------------------------------------------------------------
// Weight folding (fp32), parallel: one thread per output element.
// ---------------------------------------------------------------------------
__global__ void fold_kernel(const float* __restrict__ Wnode, const float* __restrict__ Wrbf,
                            const float* __restrict__ We1,
                            const float* __restrict__ bnode, const float* __restrict__ brbf,
                            const float* __restrict__ be1,
                            float* __restrict__ Wpa, float* __restrict__ Wqb,
                            float* __restrict__ Wc, float* __restrict__ bmsg)
{
    int l = blockIdx.y;
    int o = blockIdx.x * 256 + threadIdx.x;
    const float* We1l = We1 + (size_t)l * 384 * 128;
    if (o < 16384) {
        int r = o >> 7, c = o & 127;
        const float* A = Wnode + (size_t)l * 16384;
        float s = 0.f;
        for (int k = 0; k < 128; ++k) s += A[r * 128 + k] * We1l[k * 128 + c];
        Wpa[(size_t)l * 16384 + o] = s;
    } else if (o < 32768) {
        int oo = o - 16384;
        int r = oo >> 7, c = oo & 127;
        const float* A = Wnode + (size_t)l * 16384;
        const float* B = We1l + 16384;
        float s = 0.f;
        for (int k = 0; k < 128; ++k) s += A[r * 128 + k] * B[k * 128 + c];
        Wqb[(size_t)l * 16384 + oo] = s;
    } else if (o < 40960) {
        int oo = o - 32768;
        int r = oo >> 7, c = oo & 127;
        const float* A = Wrbf + (size_t)l * 8192;
        const float* B = We1l + 32768;
        float s = 0.f;
        for (int k = 0; k < 128; ++k) s += A[r * 128 + k] * B[k * 128 + c];
        Wc[(size_t)l * 8192 + oo] = s;
    } else if (o < 41088) {
        int j = o - 40960;
        float s = be1[l * 128 + j];
        for (int k = 0; k < 128; ++k) {
            float w = We1l[k * 128 + j] + We1l[(128 + k) * 128 + j];
            s += bnode[l * 128 + k] * w + brbf[l * 128 + k] * We1l[(256 + k) * 128 + j];
        }
        bmsg[l * 128 + j] = s;
    }
}

// ---------------------------------------------------------------------------
// Pack fp32 weight M[K][128] into per-lane MFMA B-fragment order, bf16
// ---------------------------------------------------------------------------
__global__ void pack_kernel(const float* __restrict__ M, unsigned short* __restrict__ pk, int K)
{
    int idx = blockIdx.x * 256 + threadIdx.x;
    if (idx >= K * 128) return;
    int k = idx >> 7, c = idx & 127;
    int kc = k >> 5, hi = (k >> 3) & 3, j = k & 7;
    int cbG = c >> 4, lo = c & 15;
    int lane = hi * 16 + lo;
    pk[(((kc * 8 + cbG) * 64 + lane) * 8) + j] = f2bf(M[idx]);
}

// Same, but hi/lo split pair (for node-path weights: removes B-quant error)
__global__ void pack2_kernel(const float* __restrict__ M,
                             unsigned short* __restrict__ pkh,
                             unsigned short* __restrict__ pkl, int K)
{
    int idx = blockIdx.x * 256 + threadIdx.x;
    if (idx >= K * 128) return;
    int k = idx >> 7, c = idx & 127;
    int kc = k >> 5, hi = (k >> 3) & 3, j = k & 7;
    int cbG = c >> 4, lo = c & 15;
    int lane = hi * 16 + lo;
    int o = (((kc * 8 + cbG) * 64 + lane) * 8) + j;
    float v = M[idx];
    unsigned short h = f2bf(v);
    pkh[o] = h;
    pkl[o] = f2bf(v - bf2f(h));
}

// ---------------------------------------------------------------------------
// Shared device helper: 3-term split-precision dual/single GEMM pieces are
// written inline below (kept explicit for clarity of the proven code paths).
// ---------------------------------------------------------------------------

// ---------------------------------------------------------------------------
// MFMA dual node GEMM (first layer only): P = X @ Wpa, Q = X @ Wqb; zeroes agg.
// ---------------------------------------------------------------------------
__global__ __launch_bounds__(256, 2)
void nodepq_kernel(const float* __restrict__ X,
                   const unsigned short* __restrict__ pkpah,
                   const unsigned short* __restrict__ pkpal,
                   const unsigned short* __restrict__ pkqbh,
                   const unsigned short* __restrict__ pkqbl,
                   float* __restrict__ P, float* __restrict__ Q,
                   float* __restrict__ agg)
{
    __shared__ unsigned short s_h[64 * 128];  // 16 KB, swizzled (hi)
    __shared__ unsigned short s_l[64 * 128];  // 16 KB, swizzled (lo)

    const int tid = threadIdx.x;
    const int w = tid >> 6;
    const int lane = tid & 63;
    const int lo = lane & 15, hi = lane >> 4;
    const int r0 = blockIdx.x * 64;
    const int colbase = w * 32;

    for (int i = tid; i < 1024; i += 256) {
        int e = i >> 4, cg = i & 15;
        int r = r0 + e;
        union { unsigned short u16[8]; f4 v; } H, L;
        if (r < NN) {
            f4 v0 = ((const f4*)X)[(size_t)r * 32 + cg * 2];
            f4 v1 = ((const f4*)X)[(size_t)r * 32 + cg * 2 + 1];
#pragma unroll
            for (int q = 0; q < 4; ++q) {
                unsigned short h0 = f2bf(v0[q]);
                unsigned short h1 = f2bf(v1[q]);
                H.u16[q] = h0;     L.u16[q] = f2bf(v0[q] - bf2f(h0));
                H.u16[4 + q] = h1; L.u16[4 + q] = f2bf(v1[q] - bf2f(h1));
            }
        } else {
#pragma unroll
            for (int q = 0; q < 8; ++q) { H.u16[q] = 0; L.u16[q] = 0; }
        }
        int byte = e * 256 + ((cg * 16) ^ ((e & 7) << 4));
        *reinterpret_cast<f4*>((char*)s_h + byte) = H.v;
        *reinterpret_cast<f4*>((char*)s_l + byte) = L.v;
    }
    for (int i = tid; i < 2048; i += 256) {
        int e = i >> 5, cc = i & 31;
        int r = r0 + e;
        if (r < NN) ((f4*)agg)[(size_t)r * 32 + cc] = (f4){0.f, 0.f, 0.f, 0.f};
    }
    __syncthreads();

    f32x4 accp[4][2], accq[4][2];
#pragma unroll
    for (int rb = 0; rb < 4; ++rb)
#pragma unroll
        for (int cb = 0; cb < 2; ++cb) {
            accp[rb][cb] = (f32x4){0.f, 0.f, 0.f, 0.f};
            accq[rb][cb] = (f32x4){0.f, 0.f, 0.f, 0.f};
        }

#pragma unroll
    for (int kc = 0; kc < 4; ++kc) {
        bf16x8 ah[4], al[4];
#pragma unroll
        for (int rb = 0; rb < 4; ++rb) {
            int row = rb * 16 + lo;
            int byte = row * 256 + ((kc * 64 + hi * 16) ^ ((row & 7) << 4));
            ah[rb] = *reinterpret_cast<const bf16x8*>((const char*)s_h + byte);
            al[rb] = *reinterpret_cast<const bf16x8*>((const char*)s_l + byte);
        }
#pragma unroll
        for (int cb = 0; cb < 2; ++cb) {
            size_t boff = ((size_t)((kc * 8 + w * 2 + cb) * 64 + lane)) * 8;
            bf16x8 bph = *reinterpret_cast<const bf16x8*>(pkpah + boff);
            bf16x8 bpl = *reinterpret_cast<const bf16x8*>(pkpal + boff);
            bf16x8 bqh = *reinterpret_cast<const bf16x8*>(pkqbh + boff);
            bf16x8 bql = *reinterpret_cast<const bf16x8*>(pkqbl + boff);
#pragma unroll
            for (int rb = 0; rb < 4; ++rb) {
                accp[rb][cb] = __builtin_amdgcn_mfma_f32_16x16x32_bf16(ah[rb], bph, accp[rb][cb], 0, 0, 0);
                accp[rb][cb] = __builtin_amdgcn_mfma_f32_16x16x32_bf16(al[rb], bph, accp[rb][cb], 0, 0, 0);
                accp[rb][cb] = __builtin_amdgcn_mfma_f32_16x16x32_bf16(ah[rb], bpl, accp[rb][cb], 0, 0, 0);
                accq[rb][cb] = __builtin_amdgcn_mfma_f32_16x16x32_bf16(ah[rb], bqh, accq[rb][cb], 0, 0, 0);
                accq[rb][cb] = __builtin_amdgcn_mfma_f32_16x16x32_bf16(al[rb], bqh, accq[rb][cb], 0, 0, 0);
                accq[rb][cb] = __builtin_amdgcn_mfma_f32_16x16x32_bf16(ah[rb], bql, accq[rb][cb], 0, 0, 0);
            }
        }
    }

#pragma unroll
    for (int rb = 0; rb < 4; ++rb)
#pragma unroll
        for (int r = 0; r < 4; ++r) {
            int row = r0 + rb * 16 + hi * 4 + r;
            if (row < NN) {
#pragma unroll
                for (int cb = 0; cb < 2; ++cb) {
                    int col = colbase + cb * 16 + lo;
                    P[(size_t)row * 128 + col] = accp[rb][cb][r];
                    Q[(size_t)row * 128 + col] = accq[rb][cb][r];
                }
            }
        }
}

// ---------------------------------------------------------------------------
// MFMA edge kernel (unchanged, round-13/14 proven)
// ---------------------------------------------------------------------------
__global__ __launch_bounds__(256, 4)
void edge_mfma_kernel(const float* __restrict__ P, const float* __restrict__ Q,
                      const float* __restrict__ sdist,
                      const int* __restrict__ srow, const int* __restrict__ scol,
                      const unsigned short* __restrict__ pk1,  // [2][8][64][8]
                      const unsigned short* __restrict__ pk3,  // [4][8][64][8]
                      const float* __restrict__ bmsg, const float* __restrict__ be2,
                      float* __restrict__ agg)
{
    __shared__ unsigned short s_t[EB * 128];  // 16 KB, swizzled (C1 then t, in place)
    __shared__ float s_d[EB];
    __shared__ int s_row[EB], s_col[EB];
    __shared__ int s_rs[EB + 1];
    __shared__ int s_nr;

    const int tid = threadIdx.x;
    const int w = tid >> 6;
    const int lane = tid & 63;
    const int lo = lane & 15, hi = lane >> 4;
    const int e0 = blockIdx.x * EB;
    const int ew = w * 16;                    // wave's edge window [ew, ew+16)

    if (tid < EB) {
        s_d[tid] = sdist[e0 + tid];
        s_row[tid] = srow[e0 + tid];
        s_col[tid] = scol[e0 + tid];
    }
    __syncthreads();

    if (w == 0) {
        int c = s_col[lane];
        bool flag = (lane == 0) || (c != s_col[lane - 1]);
        unsigned long long m = __ballot(flag);
        if (flag) {
            int rank = __popcll(m & ((1ull << lane) - 1ull));
            s_rs[rank] = lane;
        }
        if (lane == 0) {
            int nr = __popcll(m);
            s_nr = nr;
            s_rs[nr] = EB;
        }
    }

    // ---- phase 1: C1 = RBF @ Wc  (K = 64); A row = local edge = lo
    f32x4 acc[8];
#pragma unroll
    for (int cb = 0; cb < 8; ++cb) acc[cb] = (f32x4){0.f, 0.f, 0.f, 0.f};

    const float dvv = s_d[ew + lo];
    const float step = 6.0f / 63.0f;
#pragma unroll
    for (int kc = 0; kc < 2; ++kc) {
        union { bf16x8 v; unsigned u32[4]; } U;
#pragma unroll
        for (int j2 = 0; j2 < 4; ++j2) {
            float t0 = dvv - (float)(kc * 32 + hi * 8 + 2 * j2) * step;
            float t1 = dvv - (float)(kc * 32 + hi * 8 + 2 * j2 + 1) * step;
            U.u32[j2] = pk2bf(__expf(-10.0f * t0 * t0), __expf(-10.0f * t1 * t1));
        }
#pragma unroll
        for (int cb = 0; cb < 8; ++cb) {
            bf16x8 b = *reinterpret_cast<const bf16x8*>(
                pk1 + ((size_t)((kc * 8 + cb) * 64 + lane)) * 8);
            acc[cb] = __builtin_amdgcn_mfma_f32_16x16x32_bf16(U.v, b, acc[cb], 0, 0, 0);
        }
    }

    // ---- phase 2a: dump C1 (bf16, packed converts) into s_t at final slots
#pragma unroll
    for (int r = 0; r < 4; ++r) {
        int e = ew + hi * 4 + r;
        int sw = (e & 7) << 4;
#pragma unroll
        for (int cb = 0; cb < 8; cb += 2) {
            unsigned pk = pk2bf(acc[cb][r], acc[cb + 1][r]);
            int c0 = cb * 16 + lo, c1 = c0 + 16;
            *(unsigned short*)((char*)s_t + e * 256 + ((c0 * 2) ^ sw)) = (unsigned short)pk;
            *(unsigned short*)((char*)s_t + e * 256 + ((c1 * 2) ^ sw)) = (unsigned short)(pk >> 16);
        }
    }
    __syncthreads();

    // ---- phase 2b: coalesced f4 gather of P,Q; v = C1+P+Q+bm; t = silu(v)
    {
        const int f4c = tid & 31;           // f4-col (cols 4*f4c .. 4*f4c+3)
        const int ebase = (tid >> 5) * 8;   // 8 edges per 32-thread group
        f4 bmv = ((const f4*)bmsg)[f4c];
#pragma unroll
        for (int p = 0; p < 8; ++p) {
            int e = ebase + p;
            int nc = s_col[e], nr = s_row[e];
            f4 pv = ((const f4*)(P + (size_t)nc * 128))[f4c];
            f4 qv = ((const f4*)(Q + (size_t)nr * 128))[f4c];
            int byte = e * 256 + ((f4c * 8) ^ ((e & 7) << 4));
            unsigned long long c1 = *(unsigned long long*)((char*)s_t + byte);
            float t[4];
#pragma unroll
            for (int j = 0; j < 4; ++j) {
                float c1f = bf2f((unsigned short)(c1 >> (16 * j)));
                t[j] = silu1(c1f + pv[j] + qv[j] + bmv[j]);
            }
            unsigned lo32 = pk2bf(t[0], t[1]);
            unsigned hi32 = pk2bf(t[2], t[3]);
            *(unsigned long long*)((char*)s_t + byte) =
                (unsigned long long)lo32 | ((unsigned long long)hi32 << 32);
        }
    }
    __syncthreads();

    // ---- phase 3: M = T @ We2  (K = 128); A row = ew + lo
    f32x4 acc2[8];
#pragma unroll
    for (int cb = 0; cb < 8; ++cb) acc2[cb] = (f32x4){0.f, 0.f, 0.f, 0.f};

    {
        const int rowA = ew + lo;
        const int swA = (rowA & 7) << 4;
#pragma unroll
        for (int kc = 0; kc < 4; ++kc) {
            bf16x8 a = *reinterpret_cast<const bf16x8*>(
                (const char*)s_t + rowA * 256 + ((kc * 64 + hi * 16) ^ swA));
#pragma unroll
            for (int cb = 0; cb < 8; ++cb) {
                bf16x8 b = *reinterpret_cast<const bf16x8*>(
                    pk3 + ((size_t)((kc * 8 + cb) * 64 + lane)) * 8);
                acc2[cb] = __builtin_amdgcn_mfma_f32_16x16x32_bf16(a, b, acc2[cb], 0, 0, 0);
            }
        }
    }

    // ---- phase 4: per-run reduce clipped to this wave's window + atomicAdd
    float be2c[8];
#pragma unroll
    for (int cb = 0; cb < 8; ++cb) be2c[cb] = be2[cb * 16 + lo];

    int nruns = s_nr;
    for (int ri = 0; ri < nruns; ++ri) {
        int a0 = s_rs[ri], b0 = s_rs[ri + 1];
        if (b0 <= ew || a0 >= ew + 16) continue;   // wave-uniform skip
        int la = a0 - ew; if (la < 0) la = 0;
        int lb = b0 - ew; if (lb > 16) lb = 16;
        int node = s_col[a0];
        float s[8];
#pragma unroll
        for (int cb = 0; cb < 8; ++cb) s[cb] = 0.f;
#pragma unroll
        for (int r = 0; r < 4; ++r) {
            int el = hi * 4 + r;
            bool in = (el >= la) && (el < lb);
#pragma unroll
            for (int cb = 0; cb < 8; ++cb)
                s[cb] += in ? acc2[cb][r] : 0.f;
        }
#pragma unroll
        for (int cb = 0; cb < 8; ++cb) {
            s[cb] += __shfl_xor(s[cb], 16, 64);
            s[cb] += __shfl_xor(s[cb], 32, 64);
        }
        if (hi == 0) {
            float len = (float)(lb - la);
            float* dst = agg + (size_t)node * 128;
#pragma unroll
            for (int cb = 0; cb < 8; ++cb)
                atomicAdd(dst + cb * 16 + lo, s[cb] + len * be2c[cb]);
        }
    }
}

// ---------------------------------------------------------------------------
// FUSED node kernel (layer boundaries 0->1, 1->2, 2->3):
//   X = silu(agg @ Wu1 + b1) @ Wu2 + b2   (registers, never to global)
//   P = X @ Wpa',  Q = X @ Wqb'           (next layer's folded weights)
//   re-zeroes agg. Bit-identical math to nodeupd+nodepq (X is the same fp32
//   value, hi/lo-split from registers instead of via a global round-trip).
// ---------------------------------------------------------------------------
__global__ __launch_bounds__(256, 2)
void nodefuse_kernel(const float* __restrict__ AGG,
                     const unsigned short* __restrict__ pku1h,
                     const unsigned short* __restrict__ pku1l,
                     const float* __restrict__ bu1,
                     const unsigned short* __restrict__ pku2h,
                     const unsigned short* __restrict__ pku2l,
                     const float* __restrict__ bu2,
                     const unsigned short* __restrict__ pkpah,
                     const unsigned short* __restrict__ pkpal,
                     const unsigned short* __restrict__ pkqbh,
                     const unsigned short* __restrict__ pkqbl,
                     float* __restrict__ P, float* __restrict__ Q,
                     float* __restrict__ agg)
{
    __shared__ unsigned short s_h[64 * 128];  // 16 KB, swizzled (hi)
    __shared__ unsigned short s_l[64 * 128];  // 16 KB, swizzled (lo)

    const int tid = threadIdx.x;
    const int w = tid >> 6;
    const int lane = tid & 63;
    const int lo = lane & 15, hi = lane >> 4;
    const int r0 = blockIdx.x * 64;
    const int colbase = w * 32;

    // stage agg tile -> hi/lo bf16 swizzled LDS
    for (int i = tid; i < 1024; i += 256) {
        int e = i >> 4, cg = i & 15;
        int r = r0 + e;
        union { unsigned short u16[8]; f4 v; } H, L;
        if (r < NN) {
            f4 v0 = ((const f4*)AGG)[(size_t)r * 32 + cg * 2];
            f4 v1 = ((const f4*)AGG)[(size_t)r * 32 + cg * 2 + 1];
#pragma unroll
            for (int q = 0; q < 4; ++q) {
                unsigned short h0 = f2bf(v0[q]);
                unsigned short h1 = f2bf(v1[q]);
                H.u16[q] = h0;     L.u16[q] = f2bf(v0[q] - bf2f(h0));
                H.u16[4 + q] = h1; L.u16[4 + q] = f2bf(v1[q] - bf2f(h1));
            }
        } else {
#pragma unroll
            for (int q = 0; q < 8; ++q) { H.u16[q] = 0; L.u16[q] = 0; }
        }
        int byte = e * 256 + ((cg * 16) ^ ((e & 7) << 4));
        *reinterpret_cast<f4*>((char*)s_h + byte) = H.v;
        *reinterpret_cast<f4*>((char*)s_l + byte) = L.v;
    }
    __syncthreads();

    // re-zero agg rows for the next layer (all of this block's reads are done;
    // each block owns its own 64 rows, so no cross-block hazard)
    for (int i = tid; i < 2048; i += 256) {
        int e = i >> 5, cc = i & 31;
        int r = r0 + e;
        if (r < NN) ((f4*)agg)[(size_t)r * 32 + cc] = (f4){0.f, 0.f, 0.f, 0.f};
    }

    // ---- stage 1: t = silu(agg @ Wu1 + b1)
    f32x4 acc[4][2];
#pragma unroll
    for (int rb = 0; rb < 4; ++rb)
#pragma unroll
        for (int cb = 0; cb < 2; ++cb) acc[rb][cb] = (f32x4){0.f, 0.f, 0.f, 0.f};

#pragma unroll
    for (int kc = 0; kc < 4; ++kc) {
        bf16x8 ah[4], al[4];
#pragma unroll
        for (int rb = 0; rb < 4; ++rb) {
            int row = rb * 16 + lo;
            int byte = row * 256 + ((kc * 64 + hi * 16) ^ ((row & 7) << 4));
            ah[rb] = *reinterpret_cast<const bf16x8*>((const char*)s_h + byte);
            al[rb] = *reinterpret_cast<const bf16x8*>((const char*)s_l + byte);
        }
#pragma unroll
        for (int cb = 0; cb < 2; ++cb) {
            size_t boff = ((size_t)((kc * 8 + w * 2 + cb) * 64 + lane)) * 8;
            bf16x8 bh = *reinterpret_cast<const bf16x8*>(pku1h + boff);
            bf16x8 bl = *reinterpret_cast<const bf16x8*>(pku1l + boff);
#pragma unroll
            for (int rb = 0; rb < 4; ++rb) {
                acc[rb][cb] = __builtin_amdgcn_mfma_f32_16x16x32_bf16(ah[rb], bh, acc[rb][cb], 0, 0, 0);
                acc[rb][cb] = __builtin_amdgcn_mfma_f32_16x16x32_bf16(al[rb], bh, acc[rb][cb], 0, 0, 0);
                acc[rb][cb] = __builtin_amdgcn_mfma_f32_16x16x32_bf16(ah[rb], bl, acc[rb][cb], 0, 0, 0);
            }
        }
    }

    float b1c[2];
#pragma unroll
    for (int cb = 0; cb < 2; ++cb) b1c[cb] = bu1[colbase + cb * 16 + lo];

    __syncthreads();  // all stage-1 LDS reads complete before overwrite

#pragma unroll
    for (int rb = 0; rb < 4; ++rb)
#pragma unroll
        for (int r = 0; r < 4; ++r) {
            int row = rb * 16 + hi * 4 + r;
#pragma unroll
            for (int cb = 0; cb < 2; ++cb) {
                int col = colbase + cb * 16 + lo;
                float t = silu1(acc[rb][cb][r] + b1c[cb]);
                unsigned short th = f2bf(t);
                unsigned short tl = f2bf(t - bf2f(th));
                int byte = row * 256 + ((col * 2) ^ ((row & 7) << 4));
                *(unsigned short*)((char*)s_h + byte) = th;
                *(unsigned short*)((char*)s_l + byte) = tl;
            }
        }
    __syncthreads();

    // ---- stage 2: X = t @ Wu2 + b2 (kept in registers)
    f32x4 acc2[4][2];
#pragma unroll
    for (int rb = 0; rb < 4; ++rb)
#pragma unroll
        for (int cb = 0; cb < 2; ++cb) acc2[rb][cb] = (f32x4){0.f, 0.f, 0.f, 0.f};

#pragma unroll
    for (int kc = 0; kc < 4; ++kc) {
        bf16x8 ah[4], al[4];
#pragma unroll
        for (int rb = 0; rb < 4; ++rb) {
            int row = rb * 16 + lo;
            int byte = row * 256 + ((kc * 64 + hi * 16) ^ ((row & 7) << 4));
            ah[rb] = *reinterpret_cast<const bf16x8*>((const char*)s_h + byte);
            al[rb] = *reinterpret_cast<const bf16x8*>((const char*)s_l + byte);
        }
#pragma unroll
        for (int cb = 0; cb < 2; ++cb) {
            size_t boff = ((size_t)((kc * 8 + w * 2 + cb) * 64 + lane)) * 8;
            bf16x8 bh = *reinterpret_cast<const bf16x8*>(pku2h + boff);
            bf16x8 bl = *reinterpret_cast<const bf16x8*>(pku2l + boff);
#pragma unroll
            for (int rb = 0; rb < 4; ++rb) {
                acc2[rb][cb] = __builtin_amdgcn_mfma_f32_16x16x32_bf16(ah[rb], bh, acc2[rb][cb], 0, 0, 0);
                acc2[rb][cb] = __builtin_amdgcn_mfma_f32_16x16x32_bf16(al[rb], bh, acc2[rb][cb], 0, 0, 0);
                acc2[rb][cb] = __builtin_amdgcn_mfma_f32_16x16x32_bf16(ah[rb], bl, acc2[rb][cb], 0, 0, 0);
            }
        }
    }

    float b2c[2];
#pragma unroll
    for (int cb = 0; cb < 2; ++cb) b2c[cb] = bu2[colbase + cb * 16 + lo];

    __syncthreads();  // all stage-2 LDS reads complete before overwrite

    // ---- stage X (registers) -> hi/lo swizzled LDS for the PQ GEMM
#pragma unroll
    for (int rb = 0; rb < 4; ++rb)
#pragma unroll
        for (int r = 0; r < 4; ++r) {
            int row = rb * 16 + hi * 4 + r;
#pragma unroll
            for (int cb = 0; cb < 2; ++cb) {
                int col = colbase + cb * 16 + lo;
                float xv = acc2[rb][cb][r] + b2c[cb];
                unsigned short th = f2bf(xv);
                unsigned short tl = f2bf(xv - bf2f(th));
                int byte = row * 256 + ((col * 2) ^ ((row & 7) << 4));
                *(unsigned short*)((char*)s_h + byte) = th;
                *(unsigned short*)((char*)s_l + byte) = tl;
            }
        }
    __syncthreads();

    // ---- PQ GEMM for the next layer: P = X @ Wpa', Q = X @ Wqb'
    f32x4 accp[4][2], accq[4][2];
#pragma unroll
    for (int rb = 0; rb < 4; ++rb)
#pragma unroll
        for (int cb = 0; cb < 2; ++cb) {
            accp[rb][cb] = (f32x4){0.f, 0.f, 0.f, 0.f};
            accq[rb][cb] = (f32x4){0.f, 0.f, 0.f, 0.f};
        }

#pragma unroll
    for (int kc = 0; kc < 4; ++kc) {
        bf16x8 ah[4], al[4];
#pragma unroll
        for (int rb = 0; rb < 4; ++rb) {
            int row = rb * 16 + lo;
            int byte = row * 256 + ((kc * 64 + hi * 16) ^ ((row & 7) << 4));
            ah[rb] = *reinterpret_cast<const bf16x8*>((const char*)s_h + byte);
            al[rb] = *reinterpret_cast<const bf16x8*>((const char*)s_l + byte);
        }
#pragma unroll
        for (int cb = 0; cb < 2; ++cb) {
            size_t boff = ((size_t)((kc * 8 + w * 2 + cb) * 64 + lane)) * 8;
            bf16x8 bph = *reinterpret_cast<const bf16x8*>(pkpah + boff);
            bf16x8 bpl = *reinterpret_cast<const bf16x8*>(pkpal + boff);
            bf16x8 bqh = *reinterpret_cast<const bf16x8*>(pkqbh + boff);
            bf16x8 bql = *reinterpret_cast<const bf16x8*>(pkqbl + boff);
#pragma unroll
            for (int rb = 0; rb < 4; ++rb) {
                accp[rb][cb] = __builtin_amdgcn_mfma_f32_16x16x32_bf16(ah[rb], bph, accp[rb][cb], 0, 0, 0);
                accp[rb][cb] = __builtin_amdgcn_mfma_f32_16x16x32_bf16(al[rb], bph, accp[rb][cb], 0, 0, 0);
                accp[rb][cb] = __builtin_amdgcn_mfma_f32_16x16x32_bf16(ah[rb], bpl, accp[rb][cb], 0, 0, 0);
                accq[rb][cb] = __builtin_amdgcn_mfma_f32_16x16x32_bf16(ah[rb], bqh, accq[rb][cb], 0, 0, 0);
                accq[rb][cb] = __builtin_amdgcn_mfma_f32_16x16x32_bf16(al[rb], bqh, accq[rb][cb], 0, 0, 0);
                accq[rb][cb] = __builtin_amdgcn_mfma_f32_16x16x32_bf16(ah[rb], bql, accq[rb][cb], 0, 0, 0);
            }
        }
    }

#pragma unroll
    for (int rb = 0; rb < 4; ++rb)
#pragma unroll
        for (int r = 0; r < 4; ++r) {
            int row = r0 + rb * 16 + hi * 4 + r;
            if (row < NN) {
#pragma unroll
                for (int cb = 0; cb < 2; ++cb) {
                    int col = colbase + cb * 16 + lo;
                    P[(size_t)row * 128 + col] = accp[rb][cb][r];
                    Q[(size_t)row * 128 + col] = accq[rb][cb][r];
                }
            }
        }
}

// ---------------------------------------------------------------------------
// MFMA node update (last layer only): X_out = silu(agg@Wu1+b1)@Wu2+b2
// ---------------------------------------------------------------------------
__global__ __launch_bounds__(256, 2)
void nodeupd_kernel(const float* __restrict__ AGG,
                    const unsigned short* __restrict__ pku1h,
                    const unsigned short* __restrict__ pku1l,
                    const float* __restrict__ bu1,
                    const unsigned short* __restrict__ pku2h,
                    const unsigned short* __restrict__ pku2l,
                    const float* __restrict__ bu2,
                    float* __restrict__ Xout)
{
    __shared__ unsigned short s_h[64 * 128];  // 16 KB, swizzled (hi)
    __shared__ unsigned short s_l[64 * 128];  // 16 KB, swizzled (lo)

    const int tid = threadIdx.x;
    const int w = tid >> 6;
    const int lane = tid & 63;
    const int lo = lane & 15, hi = lane >> 4;
    const int r0 = blockIdx.x * 64;
    const int colbase = w * 32;

    for (int i = tid; i < 1024; i += 256) {
        int e = i >> 4, cg = i & 15;
        int r = r0 + e;
        union { unsigned short u16[8]; f4 v; } H, L;
        if (r < NN) {
            f4 v0 = ((const f4*)AGG)[(size_t)r * 32 + cg * 2];
            f4 v1 = ((const f4*)AGG)[(size_t)r * 32 + cg * 2 + 1];
#pragma unroll
            for (int q = 0; q < 4; ++q) {
                unsigned short h0 = f2bf(v0[q]);
                unsigned short h1 = f2bf(v1[q]);
                H.u16[q] = h0;     L.u16[q] = f2bf(v0[q] - bf2f(h0));
                H.u16[4 + q] = h1; L.u16[4 + q] = f2bf(v1[q] - bf2f(h1));
            }
        } else {
#pragma unroll
            for (int q = 0; q < 8; ++q) { H.u16[q] = 0; L.u16[q] = 0; }
        }
        int byte = e * 256 + ((cg * 16) ^ ((e & 7) << 4));
        *reinterpret_cast<f4*>((char*)s_h + byte) = H.v;
        *reinterpret_cast<f4*>((char*)s_l + byte) = L.v;
    }
    __syncthreads();

    // ---- stage 1: t = silu(agg @ Wu1 + b1)
    f32x4 acc[4][2];
#pragma unroll
    for (int rb = 0; rb < 4; ++rb)
#pragma unroll
        for (int cb = 0; cb < 2; ++cb) acc[rb][cb] = (f32x4){0.f, 0.f, 0.f, 0.f};

#pragma unroll
    for (int kc = 0; kc < 4; ++kc) {
        bf16x8 ah[4], al[4];
#pragma unroll
        for (int rb = 0; rb < 4; ++rb) {
            int row = rb * 16 + lo;
            int byte = row * 256 + ((kc * 64 + hi * 16) ^ ((row & 7) << 4));
            ah[rb] = *reinterpret_cast<const bf16x8*>((const char*)s_h + byte);
            al[rb] = *reinterpret_cast<const bf16x8*>((const char*)s_l + byte);
        }
#pragma unroll
        for (int cb = 0; cb < 2; ++cb) {
            size_t boff = ((size_t)((kc * 8 + w * 2 + cb) * 64 + lane)) * 8;
            bf16x8 bh = *reinterpret_cast<const bf16x8*>(pku1h + boff);
            bf16x8 bl = *reinterpret_cast<const bf16x8*>(pku1l + boff);
#pragma unroll
            for (int rb = 0; rb < 4; ++rb) {
                acc[rb][cb] = __builtin_amdgcn_mfma_f32_16x16x32_bf16(ah[rb], bh, acc[rb][cb], 0, 0, 0);
                acc[rb][cb] = __builtin_amdgcn_mfma_f32_16x16x32_bf16(al[rb], bh, acc[rb][cb], 0, 0, 0);
                acc[rb][cb] = __builtin_amdgcn_mfma_f32_16x16x32_bf16(ah[rb], bl, acc[rb][cb], 0, 0, 0);
            }
        }
    }

    float b1c[2];
#pragma unroll
    for (int cb = 0; cb < 2; ++cb) b1c[cb] = bu1[colbase + cb * 16 + lo];

    __syncthreads();  // all stage-1 LDS reads complete before overwrite

#pragma unroll
    for (int rb = 0; rb < 4; ++rb)
#pragma unroll
        for (int r = 0; r < 4; ++r) {
            int row = rb * 16 + hi * 4 + r;
#pragma unroll
            for (int cb = 0; cb < 2; ++cb) {
                int col = colbase + cb * 16 + lo;
                float t = silu1(acc[rb][cb][r] + b1c[cb]);
                unsigned short th = f2bf(t);
                unsigned short tl = f2bf(t - bf2f(th));
                int byte = row * 256 + ((col * 2) ^ ((row & 7) << 4));
                *(unsigned short*)((char*)s_h + byte) = th;
                *(unsigned short*)((char*)s_l + byte) = tl;
            }
        }
    __syncthreads();

    // ---- stage 2: X_out = t @ Wu2 + b2
    f32x4 acc2[4][2];
#pragma unroll
    for (int rb = 0; rb < 4; ++rb)
#pragma unroll
        for (int cb = 0; cb < 2; ++cb) acc2[rb][cb] = (f32x4){0.f, 0.f, 0.f, 0.f};

#pragma unroll
    for (int kc = 0; kc < 4; ++kc) {
        bf16x8 ah[4], al[4];
#pragma unroll
        for (int rb = 0; rb < 4; ++rb) {
            int row = rb * 16 + lo;
            int byte = row * 256 + ((kc * 64 + hi * 16) ^ ((row & 7) << 4));
            ah[rb] = *reinterpret_cast<const bf16x8*>((const char*)s_h + byte);
            al[rb] = *reinterpret_cast<const bf16x8*>((const char*)s_l + byte);
        }
#pragma unroll
        for (int cb = 0; cb < 2; ++cb) {
            size_t boff = ((size_t)((kc * 8 + w * 2 + cb) * 64 + lane)) * 8;
            bf16x8 bh = *reinterpret_cast<const bf16x8*>(pku2h + boff);
            bf16x8 bl = *reinterpret_cast<const bf16x8*>(pku2l + boff);
#pragma unroll
            for (int rb = 0; rb < 4; ++rb) {
                acc2[rb][cb] = __builtin_amdgcn_mfma_f32_16x16x32_bf16(ah[rb], bh, acc2[rb][cb], 0, 0, 0);
                acc2[rb][cb] = __builtin_amdgcn_mfma_f32_16x16x32_bf16(al[rb], bh, acc2[rb][cb], 0, 0, 0);
                acc2[rb][cb] = __builtin_amdgcn_mfma_f32_16x16x32_bf16(ah[rb], bl, acc2[rb][cb], 0, 0, 0);
            }
        }
    }

    float b2c[2];
#pragma unroll
    for (int cb = 0; cb < 2; ++cb) b2c[cb] = bu2[colbase + cb * 16 + lo];

#pragma unroll
    for (int rb = 0; rb < 4; ++rb)
#pragma unroll
        for (int r = 0; r < 4; ++r) {
            int row = r0 + rb * 16 + hi * 4 + r;
            if (row < NN) {
#pragma unroll
                for (int cb = 0; cb < 2; ++cb) {
                    int col = colbase + cb * 16 + lo;
                    Xout[(size_t)row * 128 + col] = acc2[rb][cb][r] + b2c[cb];
                }
            }
        }
}

// ---------------------------------------------------------------------------
// Graph readout: grid (G, 4); block reduces 32 cols of one graph segment
// ---------------------------------------------------------------------------
__global__ void gsum2_kernel(const float* __restrict__ X, const int* __restrict__ gstart,
                             float* __restrict__ Gm)
{
    __shared__ f4 red[32][8];
    int g = blockIdx.x;
    int q = blockIdx.y;
    int cq = threadIdx.x & 7;
    int cf = q * 8 + cq;          // f4 col (0..31)
    int rg = threadIdx.x >> 3;    // 0..31
    int i0 = gstart[g], i1 = gstart[g + 1];
    f4 s = {0.f, 0.f, 0.f, 0.f};
    for (int i = i0 + rg; i < i1; i += 32)
        s += ((const f4*)X)[(size_t)i * 32 + cf];
    red[rg][cq] = s;
    __syncthreads();
    for (int off = 16; off >= 1; off >>= 1) {
        if (rg < off) red[rg][cq] += red[rg + off][cq];
        __syncthreads();
    }
    if (rg == 0) ((f4*)Gm)[g * 32 + cf] = red[0][cq];
}

__global__ void final_kernel(const float* __restrict__ Gm,
                             const float* __restrict__ Wf1, const float* __restrict__ bf1,
                             const float* __restrict__ Wf2, const float* __restrict__ bf2,
                             float* __restrict__ out)
{
    __shared__ float red[128];
    int g = blockIdx.x;
    int j = threadIdx.x;
    float s = bf1[j];
    for (int k = 0; k < 128; ++k) s += Gm[(size_t)g * 128 + k] * Wf1[k * 128 + j];
    s = silu1(s);
    red[j] = s * Wf2[j];
    __syncthreads();
    for (int off = 64; off > 0; off >>= 1) {
        if (j < off) red[j] += red[j + off];
        __syncthreads();
    }
    if (j == 0) out[g] = red[0] + bf2[0];
}

// ---------------------------------------------------------------------------
extern "C" void kernel_launch(void* const* d_in, const int* in_sizes, int n_in,
                              void* d_out, int out_size, void* d_ws, size_t ws_size,
                              hipStream_t stream)
{
    const float* x     = (const float*)d_in[0];
    const float* pos   = (const float*)d_in[1];
    const int*   eidx  = (const int*)d_in[2];
    const int*   batch = (const int*)d_in[3];
    const float* Wnode = (const float*)d_in[4];
    const float* bnode = (const float*)d_in[5];
    const float* Wrbf  = (const float*)d_in[6];
    const float* brbf  = (const float*)d_in[7];
    const float* We1   = (const float*)d_in[8];
    const float* be1   = (const float*)d_in[9];
    const float* We2   = (const float*)d_in[10];
    const float* be2   = (const float*)d_in[11];
    const float* Wu1   = (const float*)d_in[12];
    const float* bu1   = (const float*)d_in[13];
    const float* Wu2   = (const float*)d_in[14];
    const float* bu2   = (const float*)d_in[15];
    const float* Wf1   = (const float*)d_in[16];
    const float* bf1   = (const float*)d_in[17];
    const float* Wf2   = (const float*)d_in[18];
    const float* bf2   = (const float*)d_in[19];

    const int* erow = eidx;
    const int* ecol = eidx + NE;

    char* wsb = (char*)d_ws;
    size_t off = 0;
    auto take = [&](size_t bytes) -> char* {
        char* p = wsb + off;
        off += (bytes + 255) & ~(size_t)255;
        return p;
    };
    float* Pb    = (float*)take((size_t)NN * HH * 4);
    float* Qb    = (float*)take((size_t)NN * HH * 4);
    float* aggb  = (float*)take((size_t)NN * HH * 4);
    float* xa    = (float*)take((size_t)NN * DD * 4);
    float* gm    = (float*)take((size_t)GG * DD * 4);
    float* Wpa   = (float*)take((size_t)LL * DD * HH * 4);
    float* Wqb   = (float*)take((size_t)LL * DD * HH * 4);
    float* Wcc   = (float*)take((size_t)LL * RR * HH * 4);
    float* bmsg  = (float*)take((size_t)LL * HH * 4);
    int*   cnt   = (int*)take((size_t)NN * 4);
    int*   cur   = (int*)take((size_t)NN * 4);
    int*   srow  = (int*)take((size_t)NE * 4);
    int*   scol  = (int*)take((size_t)NE * 4);
    float* sdist = (float*)take((size_t)NE * 4);
    int*   gst   = (int*)take((size_t)(GG + 1) * 4);
    unsigned short* pk1   = (unsigned short*)take((size_t)LL * RR * HH * 2);
    unsigned short* pk3   = (unsigned short*)take((size_t)LL * HH * HH * 2);
    unsigned short* pkpah = (unsigned short*)take((size_t)LL * DD * HH * 2);
    unsigned short* pkpal = (unsigned short*)take((size_t)LL * DD * HH * 2);
    unsigned short* pkqbh = (unsigned short*)take((size_t)LL * DD * HH * 2);
    unsigned short* pkqbl = (unsigned short*)take((size_t)LL * DD * HH * 2);
    unsigned short* pku1h = (unsigned short*)take((size_t)LL * HH * HH * 2);
    unsigned short* pku1l = (unsigned short*)take((size_t)LL * HH * HH * 2);
    unsigned short* pku2h = (unsigned short*)take((size_t)LL * HH * DD * 2);
    unsigned short* pku2l = (unsigned short*)take((size_t)LL * HH * DD * 2);

    if (off > ws_size) return;  // fail loudly (absmax), not a fault

    // ---- one-time preprocessing
    fillz_kernel<<<(NN + 1023) / 1024, 256, 0, stream>>>((float*)cnt, NN / 4);
    hist_kernel<<<(NE + 255) / 256, 256, 0, stream>>>(ecol, cnt);
    scan_kernel<<<1, 1024, 0, stream>>>(cnt, cur);
    scatter_kernel<<<(NE + 255) / 256, 256, 0, stream>>>(pos, erow, ecol, cur, srow, scol, sdist);
    gstart_kernel<<<(NN + 255) / 256, 256, 0, stream>>>(batch, gst);

    dim3 foldgrid((41088 + 255) / 256, LL);
    fold_kernel<<<foldgrid, 256, 0, stream>>>(Wnode, Wrbf, We1, bnode, brbf, be1,
                                              Wpa, Wqb, Wcc, bmsg);
    for (int l = 0; l < LL; ++l) {
        pack_kernel<<<(RR * HH + 255) / 256, 256, 0, stream>>>(
            Wcc + (size_t)l * RR * HH, pk1 + (size_t)l * RR * HH, RR);
        pack_kernel<<<(HH * HH + 255) / 256, 256, 0, stream>>>(
            We2 + (size_t)l * HH * HH, pk3 + (size_t)l * HH * HH, HH);
        pack2_kernel<<<(DD * HH + 255) / 256, 256, 0, stream>>>(
            Wpa + (size_t)l * DD * HH, pkpah + (size_t)l * DD * HH,
            pkpal + (size_t)l * DD * HH, DD);
        pack2_kernel<<<(DD * HH + 255) / 256, 256, 0, stream>>>(
            Wqb + (size_t)l * DD * HH, pkqbh + (size_t)l * DD * HH,
            pkqbl + (size_t)l * DD * HH, DD);
        pack2_kernel<<<(HH * HH + 255) / 256, 256, 0, stream>>>(
            Wu1 + (size_t)l * HH * HH, pku1h + (size_t)l * HH * HH,
            pku1l + (size_t)l * HH * HH, HH);
        pack2_kernel<<<(HH * DD + 255) / 256, 256, 0, stream>>>(
            Wu2 + (size_t)l * HH * DD, pku2h + (size_t)l * HH * DD,
            pku2l + (size_t)l * HH * DD, HH);
    }

    // ---- layers (fused node path: X never round-trips through HBM)
    const int nblk = (NN + 63) / 64;
    nodepq_kernel<<<nblk, 256, 0, stream>>>(x, pkpah, pkpal, pkqbh, pkqbl,
                                            Pb, Qb, aggb);
    for (int l = 0; l < LL; ++l) {
        edge_mfma_kernel<<<NE / EB, 256, 0, stream>>>(Pb, Qb, sdist, srow, scol,
                                                      pk1 + (size_t)l * RR * HH,
                                                      pk3 + (size_t)l * HH * HH,
                                                      bmsg + (size_t)l * HH,
                                                      be2 + (size_t)l * HH, aggb);
        if (l < LL - 1) {
            nodefuse_kernel<<<nblk, 256, 0, stream>>>(
                aggb,
                pku1h + (size_t)l * HH * HH, pku1l + (size_t)l * HH * HH,
                bu1 + (size_t)l * HH,
                pku2h + (size_t)l * HH * DD, pku2l + (size_t)l * HH * DD,
                bu2 + (size_t)l * DD,
                pkpah + (size_t)(l + 1) * DD * HH, pkpal + (size_t)(l + 1) * DD * HH,
                pkqbh + (size_t)(l + 1) * DD * HH, pkqbl + (size_t)(l + 1) * DD * HH,
                Pb, Qb, aggb);
        } else {
            nodeupd_kernel<<<nblk, 256, 0, stream>>>(
                aggb,
                pku1h + (size_t)l * HH * HH, pku1l + (size_t)l * HH * HH,
                bu1 + (size_t)l * HH,
                pku2h + (size_t)l * HH * DD, pku2l + (size_t)l * HH * DD,
                bu2 + (size_t)l * DD, xa);
        }
    }

    dim3 gsgrid(GG, 4);
    gsum2_kernel<<<gsgrid, 256, 0, stream>>>(xa, gst, gm);
    final_kernel<<<GG, 128, 0, stream>>>(gm, Wf1, bf1, Wf2, bf2, (float*)d_out);
}

// Round 16
// 857.483 us; speedup vs baseline: 1.0770x; 1.0668x over previous
//
#include <hip/hip_runtime.h>
#include <hip/hip_bf16.h>

#define NN 50000   // nodes
#define NE 800000  // edges
#define DD 128     // node dim
#define HH 128     // hidden dim
#define RR 64      // num rbf
#define LL 4       // layers
#define GG 64      // graphs
#define EB 64      // edges per block (edge kernel)

typedef float f4 __attribute__((ext_vector_type(4)));
typedef __attribute__((ext_vector_type(8))) short bf16x8;  // MFMA A/B frag (4 VGPR)
typedef __attribute__((ext_vector_type(4))) float f32x4;   // MFMA C/D frag

// silu via hardware rcp (~1 ulp; way below bf16 quantum).
__device__ __forceinline__ float silu1(float v)
{
    return v * __builtin_amdgcn_rcpf(1.0f + __expf(-v));
}

// RNE float -> bf16 bits (branchless; inputs finite)
__device__ __forceinline__ unsigned short f2bf(float f)
{
    union { float f; unsigned u; } x; x.f = f;
    unsigned r = x.u + 0x7fffu + ((x.u >> 16) & 1u);
    return (unsigned short)(r >> 16);
}
__device__ __forceinline__ float bf2f(unsigned short h)
{
    union { unsigned u; float f; } x; x.u = ((unsigned)h) << 16; return x.f;
}
// Packed RNE pair convert via the official HIP API
__device__ __forceinline__ unsigned pk2bf(float a, float b)
{
    __hip_bfloat162 h = __float22bfloat162_rn(float2{a, b});
    union { __hip_bfloat162 h; unsigned u; } c; c.h = h;
    return c.u;
}

// ---------------------------------------------------------------------------
// Zero fill
// ---------------------------------------------------------------------------
__global__ void fillz_kernel(float* __restrict__ p, int n4)
{
    int i = blockIdx.x * 256 + threadIdx.x;
    if (i < n4) ((f4*)p)[i] = (f4){0.f, 0.f, 0.f, 0.f};
}

// ---------------------------------------------------------------------------
// Counting sort of edges by col (destination). One-time per call.
// ---------------------------------------------------------------------------
__global__ void hist_kernel(const int* __restrict__ ecol, int* __restrict__ cnt)
{
    int e = blockIdx.x * 256 + threadIdx.x;
    if (e < NE) atomicAdd(&cnt[ecol[e]], 1);
}

__global__ void scan_kernel(const int* __restrict__ cnt, int* __restrict__ cur)
{
    __shared__ int s[1024];
    int t = threadIdx.x;               // 1024 threads, 1 block
    const int CH = 49;                 // 1024*49 = 50176 >= NN
    int a0 = t * CH, a1 = a0 + CH; if (a1 > NN) a1 = NN; if (a0 > NN) a0 = NN;
    int s0 = 0;
    for (int i = a0; i < a1; ++i) s0 += cnt[i];
    s[t] = s0;
    __syncthreads();
    for (int off = 1; off < 1024; off <<= 1) {
        int v = (t >= off) ? s[t - off] : 0;
        __syncthreads();
        s[t] += v;
        __syncthreads();
    }
    int base = (t == 0) ? 0 : s[t - 1];
    for (int i = a0; i < a1; ++i) { cur[i] = base; base += cnt[i]; }
}

__global__ void scatter_kernel(const float* __restrict__ pos,
                               const int* __restrict__ erow, const int* __restrict__ ecol,
                               int* __restrict__ cur,
                               int* __restrict__ srow, int* __restrict__ scol,
                               float* __restrict__ sdist)
{
    int e = blockIdx.x * 256 + threadIdx.x;
    if (e >= NE) return;
    int r = erow[e], c = ecol[e];
    int p = atomicAdd(&cur[c], 1);
    srow[p] = r;
    scol[p] = c;
    float dx = pos[r * 3 + 0] - pos[c * 3 + 0];
    float dy = pos[r * 3 + 1] - pos[c * 3 + 1];
    float dz = pos[r * 3 + 2] - pos[c * 3 + 2];
    sdist[p] = sqrtf(dx * dx + dy * dy + dz * dz);
}

// ---------------------------------------------------------------------------
// Graph segment boundaries from sorted batch
// ---------------------------------------------------------------------------
__global__ void gstart_kernel(const int* __restrict__ batch, int* __restrict__ gstart)
{
    int i = blockIdx.x * 256 + threadIdx.x;
    if (i >= NN) return;
    int b = batch[i];
    if (i == 0) {
        for (int g = 0; g <= b; ++g) gstart[g] = 0;
    } else {
        int bp = batch[i - 1];
        for (int g = bp + 1; g <= b; ++g) gstart[g] = i;
    }
    if (i == NN - 1) {
        for (int g = b + 1; g <= GG; ++g) gstart[g] = NN;
    }
}

// ---------------------------------------------------------------------------
// Weight folding (fp32), parallel: one thread per output element.
// ---------------------------------------------------------------------------
__global__ void fold_kernel(const float* __restrict__ Wnode, const float* __restrict__ Wrbf,
                            const float* __restrict__ We1,
                            const float* __restrict__ bnode, const float* __restrict__ brbf,
                            const float* __restrict__ be1,
                            float* __restrict__ Wpa, float* __restrict__ Wqb,
                            float* __restrict__ Wc, float* __restrict__ bmsg)
{
    int l = blockIdx.y;
    int o = blockIdx.x * 256 + threadIdx.x;
    const float* We1l = We1 + (size_t)l * 384 * 128;
    if (o < 16384) {
        int r = o >> 7, c = o & 127;
        const float* A = Wnode + (size_t)l * 16384;
        float s = 0.f;
        for (int k = 0; k < 128; ++k) s += A[r * 128 + k] * We1l[k * 128 + c];
        Wpa[(size_t)l * 16384 + o] = s;
    } else if (o < 32768) {
        int oo = o - 16384;
        int r = oo >> 7, c = oo & 127;
        const float* A = Wnode + (size_t)l * 16384;
        const float* B = We1l + 16384;
        float s = 0.f;
        for (int k = 0; k < 128; ++k) s += A[r * 128 + k] * B[k * 128 + c];
        Wqb[(size_t)l * 16384 + oo] = s;
    } else if (o < 40960) {
        int oo = o - 32768;
        int r = oo >> 7, c = oo & 127;
        const float* A = Wrbf + (size_t)l * 8192;
        const float* B = We1l + 32768;
        float s = 0.f;
        for (int k = 0; k < 128; ++k) s += A[r * 128 + k] * B[k * 128 + c];
        Wc[(size_t)l * 8192 + oo] = s;
    } else if (o < 41088) {
        int j = o - 40960;
        float s = be1[l * 128 + j];
        for (int k = 0; k < 128; ++k) {
            float w = We1l[k * 128 + j] + We1l[(128 + k) * 128 + j];
            s += bnode[l * 128 + k] * w + brbf[l * 128 + k] * We1l[(256 + k) * 128 + j];
        }
        bmsg[l * 128 + j] = s;
    }
}

// ---------------------------------------------------------------------------
// Merged pack kernel: all 6 weight packings for one layer in one launch.
// Segment map per layer (element offsets):
//   [0,8192)       pk1  <- Wcc   (pack,  K=64)
//   [8192,24576)   pk3  <- We2   (pack,  K=128)
//   [24576,40960)  pkpa <- Wpa   (pack2, K=128)
//   [40960,57344)  pkqb <- Wqb   (pack2, K=128)
//   [57344,73728)  pku1 <- Wu1   (pack2, K=128)
//   [73728,90112)  pku2 <- Wu2   (pack2, K=128)
// grid = (352, LL). Identical arithmetic to the old pack/pack2 kernels.
// ---------------------------------------------------------------------------
__global__ void packall_kernel(const float* __restrict__ Wcc, const float* __restrict__ We2,
                               const float* __restrict__ Wpa, const float* __restrict__ Wqb,
                               const float* __restrict__ Wu1, const float* __restrict__ Wu2,
                               unsigned short* __restrict__ pk1, unsigned short* __restrict__ pk3,
                               unsigned short* __restrict__ pkpah, unsigned short* __restrict__ pkpal,
                               unsigned short* __restrict__ pkqbh, unsigned short* __restrict__ pkqbl,
                               unsigned short* __restrict__ pku1h, unsigned short* __restrict__ pku1l,
                               unsigned short* __restrict__ pku2h, unsigned short* __restrict__ pku2l)
{
    int l = blockIdx.y;
    int g = blockIdx.x * 256 + threadIdx.x;
    if (g >= 90112) return;

    const float* src;
    unsigned short* dsth;
    unsigned short* dstl = nullptr;  // null -> single-precision pack
    int idx;
    if (g < 8192) {
        idx = g;            src = Wcc + (size_t)l * 8192;  dsth = pk1 + (size_t)l * 8192;
    } else if (g < 24576) {
        idx = g - 8192;     src = We2 + (size_t)l * 16384; dsth = pk3 + (size_t)l * 16384;
    } else if (g < 40960) {
        idx = g - 24576;    src = Wpa + (size_t)l * 16384;
        dsth = pkpah + (size_t)l * 16384; dstl = pkpal + (size_t)l * 16384;
    } else if (g < 57344) {
        idx = g - 40960;    src = Wqb + (size_t)l * 16384;
        dsth = pkqbh + (size_t)l * 16384; dstl = pkqbl + (size_t)l * 16384;
    } else if (g < 73728) {
        idx = g - 57344;    src = Wu1 + (size_t)l * 16384;
        dsth = pku1h + (size_t)l * 16384; dstl = pku1l + (size_t)l * 16384;
    } else {
        idx = g - 73728;    src = Wu2 + (size_t)l * 16384;
        dsth = pku2h + (size_t)l * 16384; dstl = pku2l + (size_t)l * 16384;
    }

    int k = idx >> 7, c = idx & 127;
    int kc = k >> 5, hi = (k >> 3) & 3, j = k & 7;
    int cbG = c >> 4, lo = c & 15;
    int lane = hi * 16 + lo;
    int o = (((kc * 8 + cbG) * 64 + lane) * 8) + j;
    float v = src[idx];
    unsigned short h = f2bf(v);
    dsth[o] = h;
    if (dstl) dstl[o] = f2bf(v - bf2f(h));
}

// ---------------------------------------------------------------------------
// MFMA dual node GEMM (first layer only): P = X @ Wpa, Q = X @ Wqb; zeroes agg.
// ---------------------------------------------------------------------------
__global__ __launch_bounds__(256, 2)
void nodepq_kernel(const float* __restrict__ X,
                   const unsigned short* __restrict__ pkpah,
                   const unsigned short* __restrict__ pkpal,
                   const unsigned short* __restrict__ pkqbh,
                   const unsigned short* __restrict__ pkqbl,
                   float* __restrict__ P, float* __restrict__ Q,
                   float* __restrict__ agg)
{
    __shared__ unsigned short s_h[64 * 128];  // 16 KB, swizzled (hi)
    __shared__ unsigned short s_l[64 * 128];  // 16 KB, swizzled (lo)

    const int tid = threadIdx.x;
    const int w = tid >> 6;
    const int lane = tid & 63;
    const int lo = lane & 15, hi = lane >> 4;
    const int r0 = blockIdx.x * 64;
    const int colbase = w * 32;

    for (int i = tid; i < 1024; i += 256) {
        int e = i >> 4, cg = i & 15;
        int r = r0 + e;
        union { unsigned short u16[8]; f4 v; } H, L;
        if (r < NN) {
            f4 v0 = ((const f4*)X)[(size_t)r * 32 + cg * 2];
            f4 v1 = ((const f4*)X)[(size_t)r * 32 + cg * 2 + 1];
#pragma unroll
            for (int q = 0; q < 4; ++q) {
                unsigned short h0 = f2bf(v0[q]);
                unsigned short h1 = f2bf(v1[q]);
                H.u16[q] = h0;     L.u16[q] = f2bf(v0[q] - bf2f(h0));
                H.u16[4 + q] = h1; L.u16[4 + q] = f2bf(v1[q] - bf2f(h1));
            }
        } else {
#pragma unroll
            for (int q = 0; q < 8; ++q) { H.u16[q] = 0; L.u16[q] = 0; }
        }
        int byte = e * 256 + ((cg * 16) ^ ((e & 7) << 4));
        *reinterpret_cast<f4*>((char*)s_h + byte) = H.v;
        *reinterpret_cast<f4*>((char*)s_l + byte) = L.v;
    }
    for (int i = tid; i < 2048; i += 256) {
        int e = i >> 5, cc = i & 31;
        int r = r0 + e;
        if (r < NN) ((f4*)agg)[(size_t)r * 32 + cc] = (f4){0.f, 0.f, 0.f, 0.f};
    }
    __syncthreads();

    f32x4 accp[4][2], accq[4][2];
#pragma unroll
    for (int rb = 0; rb < 4; ++rb)
#pragma unroll
        for (int cb = 0; cb < 2; ++cb) {
            accp[rb][cb] = (f32x4){0.f, 0.f, 0.f, 0.f};
            accq[rb][cb] = (f32x4){0.f, 0.f, 0.f, 0.f};
        }

#pragma unroll
    for (int kc = 0; kc < 4; ++kc) {
        bf16x8 ah[4], al[4];
#pragma unroll
        for (int rb = 0; rb < 4; ++rb) {
            int row = rb * 16 + lo;
            int byte = row * 256 + ((kc * 64 + hi * 16) ^ ((row & 7) << 4));
            ah[rb] = *reinterpret_cast<const bf16x8*>((const char*)s_h + byte);
            al[rb] = *reinterpret_cast<const bf16x8*>((const char*)s_l + byte);
        }
#pragma unroll
        for (int cb = 0; cb < 2; ++cb) {
            size_t boff = ((size_t)((kc * 8 + w * 2 + cb) * 64 + lane)) * 8;
            bf16x8 bph = *reinterpret_cast<const bf16x8*>(pkpah + boff);
            bf16x8 bpl = *reinterpret_cast<const bf16x8*>(pkpal + boff);
            bf16x8 bqh = *reinterpret_cast<const bf16x8*>(pkqbh + boff);
            bf16x8 bql = *reinterpret_cast<const bf16x8*>(pkqbl + boff);
#pragma unroll
            for (int rb = 0; rb < 4; ++rb) {
                accp[rb][cb] = __builtin_amdgcn_mfma_f32_16x16x32_bf16(ah[rb], bph, accp[rb][cb], 0, 0, 0);
                accp[rb][cb] = __builtin_amdgcn_mfma_f32_16x16x32_bf16(al[rb], bph, accp[rb][cb], 0, 0, 0);
                accp[rb][cb] = __builtin_amdgcn_mfma_f32_16x16x32_bf16(ah[rb], bpl, accp[rb][cb], 0, 0, 0);
                accq[rb][cb] = __builtin_amdgcn_mfma_f32_16x16x32_bf16(ah[rb], bqh, accq[rb][cb], 0, 0, 0);
                accq[rb][cb] = __builtin_amdgcn_mfma_f32_16x16x32_bf16(al[rb], bqh, accq[rb][cb], 0, 0, 0);
                accq[rb][cb] = __builtin_amdgcn_mfma_f32_16x16x32_bf16(ah[rb], bql, accq[rb][cb], 0, 0, 0);
            }
        }
    }

#pragma unroll
    for (int rb = 0; rb < 4; ++rb)
#pragma unroll
        for (int r = 0; r < 4; ++r) {
            int row = r0 + rb * 16 + hi * 4 + r;
            if (row < NN) {
#pragma unroll
                for (int cb = 0; cb < 2; ++cb) {
                    int col = colbase + cb * 16 + lo;
                    P[(size_t)row * 128 + col] = accp[rb][cb][r];
                    Q[(size_t)row * 128 + col] = accq[rb][cb][r];
                }
            }
        }
}

// ---------------------------------------------------------------------------
// MFMA edge kernel (unchanged, proven)
// ---------------------------------------------------------------------------
__global__ __launch_bounds__(256, 4)
void edge_mfma_kernel(const float* __restrict__ P, const float* __restrict__ Q,
                      const float* __restrict__ sdist,
                      const int* __restrict__ srow, const int* __restrict__ scol,
                      const unsigned short* __restrict__ pk1,  // [2][8][64][8]
                      const unsigned short* __restrict__ pk3,  // [4][8][64][8]
                      const float* __restrict__ bmsg, const float* __restrict__ be2,
                      float* __restrict__ agg)
{
    __shared__ unsigned short s_t[EB * 128];  // 16 KB, swizzled (C1 then t, in place)
    __shared__ float s_d[EB];
    __shared__ int s_row[EB], s_col[EB];
    __shared__ int s_rs[EB + 1];
    __shared__ int s_nr;

    const int tid = threadIdx.x;
    const int w = tid >> 6;
    const int lane = tid & 63;
    const int lo = lane & 15, hi = lane >> 4;
    const int e0 = blockIdx.x * EB;
    const int ew = w * 16;                    // wave's edge window [ew, ew+16)

    if (tid < EB) {
        s_d[tid] = sdist[e0 + tid];
        s_row[tid] = srow[e0 + tid];
        s_col[tid] = scol[e0 + tid];
    }
    __syncthreads();

    if (w == 0) {
        int c = s_col[lane];
        bool flag = (lane == 0) || (c != s_col[lane - 1]);
        unsigned long long m = __ballot(flag);
        if (flag) {
            int rank = __popcll(m & ((1ull << lane) - 1ull));
            s_rs[rank] = lane;
        }
        if (lane == 0) {
            int nr = __popcll(m);
            s_nr = nr;
            s_rs[nr] = EB;
        }
    }

    // ---- phase 1: C1 = RBF @ Wc  (K = 64); A row = local edge = lo
    f32x4 acc[8];
#pragma unroll
    for (int cb = 0; cb < 8; ++cb) acc[cb] = (f32x4){0.f, 0.f, 0.f, 0.f};

    const float dvv = s_d[ew + lo];
    const float step = 6.0f / 63.0f;
#pragma unroll
    for (int kc = 0; kc < 2; ++kc) {
        union { bf16x8 v; unsigned u32[4]; } U;
#pragma unroll
        for (int j2 = 0; j2 < 4; ++j2) {
            float t0 = dvv - (float)(kc * 32 + hi * 8 + 2 * j2) * step;
            float t1 = dvv - (float)(kc * 32 + hi * 8 + 2 * j2 + 1) * step;
            U.u32[j2] = pk2bf(__expf(-10.0f * t0 * t0), __expf(-10.0f * t1 * t1));
        }
#pragma unroll
        for (int cb = 0; cb < 8; ++cb) {
            bf16x8 b = *reinterpret_cast<const bf16x8*>(
                pk1 + ((size_t)((kc * 8 + cb) * 64 + lane)) * 8);
            acc[cb] = __builtin_amdgcn_mfma_f32_16x16x32_bf16(U.v, b, acc[cb], 0, 0, 0);
        }
    }

    // ---- phase 2a: dump C1 (bf16, packed converts) into s_t at final slots
#pragma unroll
    for (int r = 0; r < 4; ++r) {
        int e = ew + hi * 4 + r;
        int sw = (e & 7) << 4;
#pragma unroll
        for (int cb = 0; cb < 8; cb += 2) {
            unsigned pk = pk2bf(acc[cb][r], acc[cb + 1][r]);
            int c0 = cb * 16 + lo, c1 = c0 + 16;
            *(unsigned short*)((char*)s_t + e * 256 + ((c0 * 2) ^ sw)) = (unsigned short)pk;
            *(unsigned short*)((char*)s_t + e * 256 + ((c1 * 2) ^ sw)) = (unsigned short)(pk >> 16);
        }
    }
    __syncthreads();

    // ---- phase 2b: coalesced f4 gather of P,Q; v = C1+P+Q+bm; t = silu(v)
    {
        const int f4c = tid & 31;           // f4-col (cols 4*f4c .. 4*f4c+3)
        const int ebase = (tid >> 5) * 8;   // 8 edges per 32-thread group
        f4 bmv = ((const f4*)bmsg)[f4c];
#pragma unroll
        for (int p = 0; p < 8; ++p) {
            int e = ebase + p;
            int nc = s_col[e], nr = s_row[e];
            f4 pv = ((const f4*)(P + (size_t)nc * 128))[f4c];
            f4 qv = ((const f4*)(Q + (size_t)nr * 128))[f4c];
            int byte = e * 256 + ((f4c * 8) ^ ((e & 7) << 4));
            unsigned long long c1 = *(unsigned long long*)((char*)s_t + byte);
            float t[4];
#pragma unroll
            for (int j = 0; j < 4; ++j) {
                float c1f = bf2f((unsigned short)(c1 >> (16 * j)));
                t[j] = silu1(c1f + pv[j] + qv[j] + bmv[j]);
            }
            unsigned lo32 = pk2bf(t[0], t[1]);
            unsigned hi32 = pk2bf(t[2], t[3]);
            *(unsigned long long*)((char*)s_t + byte) =
                (unsigned long long)lo32 | ((unsigned long long)hi32 << 32);
        }
    }
    __syncthreads();

    // ---- phase 3: M = T @ We2  (K = 128); A row = ew + lo
    f32x4 acc2[8];
#pragma unroll
    for (int cb = 0; cb < 8; ++cb) acc2[cb] = (f32x4){0.f, 0.f, 0.f, 0.f};

    {
        const int rowA = ew + lo;
        const int swA = (rowA & 7) << 4;
#pragma unroll
        for (int kc = 0; kc < 4; ++kc) {
            bf16x8 a = *reinterpret_cast<const bf16x8*>(
                (const char*)s_t + rowA * 256 + ((kc * 64 + hi * 16) ^ swA));
#pragma unroll
            for (int cb = 0; cb < 8; ++cb) {
                bf16x8 b = *reinterpret_cast<const bf16x8*>(
                    pk3 + ((size_t)((kc * 8 + cb) * 64 + lane)) * 8);
                acc2[cb] = __builtin_amdgcn_mfma_f32_16x16x32_bf16(a, b, acc2[cb], 0, 0, 0);
            }
        }
    }

    // ---- phase 4: per-run reduce clipped to this wave's window + atomicAdd
    float be2c[8];
#pragma unroll
    for (int cb = 0; cb < 8; ++cb) be2c[cb] = be2[cb * 16 + lo];

    int nruns = s_nr;
    for (int ri = 0; ri < nruns; ++ri) {
        int a0 = s_rs[ri], b0 = s_rs[ri + 1];
        if (b0 <= ew || a0 >= ew + 16) continue;   // wave-uniform skip
        int la = a0 - ew; if (la < 0) la = 0;
        int lb = b0 - ew; if (lb > 16) lb = 16;
        int node = s_col[a0];
        float s[8];
#pragma unroll
        for (int cb = 0; cb < 8; ++cb) s[cb] = 0.f;
#pragma unroll
        for (int r = 0; r < 4; ++r) {
            int el = hi * 4 + r;
            bool in = (el >= la) && (el < lb);
#pragma unroll
            for (int cb = 0; cb < 8; ++cb)
                s[cb] += in ? acc2[cb][r] : 0.f;
        }
#pragma unroll
        for (int cb = 0; cb < 8; ++cb) {
            s[cb] += __shfl_xor(s[cb], 16, 64);
            s[cb] += __shfl_xor(s[cb], 32, 64);
        }
        if (hi == 0) {
            float len = (float)(lb - la);
            float* dst = agg + (size_t)node * 128;
#pragma unroll
            for (int cb = 0; cb < 8; ++cb)
                atomicAdd(dst + cb * 16 + lo, s[cb] + len * be2c[cb]);
        }
    }
}

// ---------------------------------------------------------------------------
// FUSED node kernel (layer boundaries): X in registers; P,Q for next layer.
// ---------------------------------------------------------------------------
__global__ __launch_bounds__(256, 2)
void nodefuse_kernel(const float* __restrict__ AGG,
                     const unsigned short* __restrict__ pku1h,
                     const unsigned short* __restrict__ pku1l,
                     const float* __restrict__ bu1,
                     const unsigned short* __restrict__ pku2h,
                     const unsigned short* __restrict__ pku2l,
                     const float* __restrict__ bu2,
                     const unsigned short* __restrict__ pkpah,
                     const unsigned short* __restrict__ pkpal,
                     const unsigned short* __restrict__ pkqbh,
                     const unsigned short* __restrict__ pkqbl,
                     float* __restrict__ P, float* __restrict__ Q,
                     float* __restrict__ agg)
{
    __shared__ unsigned short s_h[64 * 128];  // 16 KB, swizzled (hi)
    __shared__ unsigned short s_l[64 * 128];  // 16 KB, swizzled (lo)

    const int tid = threadIdx.x;
    const int w = tid >> 6;
    const int lane = tid & 63;
    const int lo = lane & 15, hi = lane >> 4;
    const int r0 = blockIdx.x * 64;
    const int colbase = w * 32;

    for (int i = tid; i < 1024; i += 256) {
        int e = i >> 4, cg = i & 15;
        int r = r0 + e;
        union { unsigned short u16[8]; f4 v; } H, L;
        if (r < NN) {
            f4 v0 = ((const f4*)AGG)[(size_t)r * 32 + cg * 2];
            f4 v1 = ((const f4*)AGG)[(size_t)r * 32 + cg * 2 + 1];
#pragma unroll
            for (int q = 0; q < 4; ++q) {
                unsigned short h0 = f2bf(v0[q]);
                unsigned short h1 = f2bf(v1[q]);
                H.u16[q] = h0;     L.u16[q] = f2bf(v0[q] - bf2f(h0));
                H.u16[4 + q] = h1; L.u16[4 + q] = f2bf(v1[q] - bf2f(h1));
            }
        } else {
#pragma unroll
            for (int q = 0; q < 8; ++q) { H.u16[q] = 0; L.u16[q] = 0; }
        }
        int byte = e * 256 + ((cg * 16) ^ ((e & 7) << 4));
        *reinterpret_cast<f4*>((char*)s_h + byte) = H.v;
        *reinterpret_cast<f4*>((char*)s_l + byte) = L.v;
    }
    __syncthreads();

    // re-zero agg rows for the next layer
    for (int i = tid; i < 2048; i += 256) {
        int e = i >> 5, cc = i & 31;
        int r = r0 + e;
        if (r < NN) ((f4*)agg)[(size_t)r * 32 + cc] = (f4){0.f, 0.f, 0.f, 0.f};
    }

    // ---- stage 1: t = silu(agg @ Wu1 + b1)
    f32x4 acc[4][2];
#pragma unroll
    for (int rb = 0; rb < 4; ++rb)
#pragma unroll
        for (int cb = 0; cb < 2; ++cb) acc[rb][cb] = (f32x4){0.f, 0.f, 0.f, 0.f};

#pragma unroll
    for (int kc = 0; kc < 4; ++kc) {
        bf16x8 ah[4], al[4];
#pragma unroll
        for (int rb = 0; rb < 4; ++rb) {
            int row = rb * 16 + lo;
            int byte = row * 256 + ((kc * 64 + hi * 16) ^ ((row & 7) << 4));
            ah[rb] = *reinterpret_cast<const bf16x8*>((const char*)s_h + byte);
            al[rb] = *reinterpret_cast<const bf16x8*>((const char*)s_l + byte);
        }
#pragma unroll
        for (int cb = 0; cb < 2; ++cb) {
            size_t boff = ((size_t)((kc * 8 + w * 2 + cb) * 64 + lane)) * 8;
            bf16x8 bh = *reinterpret_cast<const bf16x8*>(pku1h + boff);
            bf16x8 bl = *reinterpret_cast<const bf16x8*>(pku1l + boff);
#pragma unroll
            for (int rb = 0; rb < 4; ++rb) {
                acc[rb][cb] = __builtin_amdgcn_mfma_f32_16x16x32_bf16(ah[rb], bh, acc[rb][cb], 0, 0, 0);
                acc[rb][cb] = __builtin_amdgcn_mfma_f32_16x16x32_bf16(al[rb], bh, acc[rb][cb], 0, 0, 0);
                acc[rb][cb] = __builtin_amdgcn_mfma_f32_16x16x32_bf16(ah[rb], bl, acc[rb][cb], 0, 0, 0);
            }
        }
    }

    float b1c[2];
#pragma unroll
    for (int cb = 0; cb < 2; ++cb) b1c[cb] = bu1[colbase + cb * 16 + lo];

    __syncthreads();

#pragma unroll
    for (int rb = 0; rb < 4; ++rb)
#pragma unroll
        for (int r = 0; r < 4; ++r) {
            int row = rb * 16 + hi * 4 + r;
#pragma unroll
            for (int cb = 0; cb < 2; ++cb) {
                int col = colbase + cb * 16 + lo;
                float t = silu1(acc[rb][cb][r] + b1c[cb]);
                unsigned short th = f2bf(t);
                unsigned short tl = f2bf(t - bf2f(th));
                int byte = row * 256 + ((col * 2) ^ ((row & 7) << 4));
                *(unsigned short*)((char*)s_h + byte) = th;
                *(unsigned short*)((char*)s_l + byte) = tl;
            }
        }
    __syncthreads();

    // ---- stage 2: X = t @ Wu2 + b2 (kept in registers)
    f32x4 acc2[4][2];
#pragma unroll
    for (int rb = 0; rb < 4; ++rb)
#pragma unroll
        for (int cb = 0; cb < 2; ++cb) acc2[rb][cb] = (f32x4){0.f, 0.f, 0.f, 0.f};

#pragma unroll
    for (int kc = 0; kc < 4; ++kc) {
        bf16x8 ah[4], al[4];
#pragma unroll
        for (int rb = 0; rb < 4; ++rb) {
            int row = rb * 16 + lo;
            int byte = row * 256 + ((kc * 64 + hi * 16) ^ ((row & 7) << 4));
            ah[rb] = *reinterpret_cast<const bf16x8*>((const char*)s_h + byte);
            al[rb] = *reinterpret_cast<const bf16x8*>((const char*)s_l + byte);
        }
#pragma unroll
        for (int cb = 0; cb < 2; ++cb) {
            size_t boff = ((size_t)((kc * 8 + w * 2 + cb) * 64 + lane)) * 8;
            bf16x8 bh = *reinterpret_cast<const bf16x8*>(pku2h + boff);
            bf16x8 bl = *reinterpret_cast<const bf16x8*>(pku2l + boff);
#pragma unroll
            for (int rb = 0; rb < 4; ++rb) {
                acc2[rb][cb] = __builtin_amdgcn_mfma_f32_16x16x32_bf16(ah[rb], bh, acc2[rb][cb], 0, 0, 0);
                acc2[rb][cb] = __builtin_amdgcn_mfma_f32_16x16x32_bf16(al[rb], bh, acc2[rb][cb], 0, 0, 0);
                acc2[rb][cb] = __builtin_amdgcn_mfma_f32_16x16x32_bf16(ah[rb], bl, acc2[rb][cb], 0, 0, 0);
            }
        }
    }

    float b2c[2];
#pragma unroll
    for (int cb = 0; cb < 2; ++cb) b2c[cb] = bu2[colbase + cb * 16 + lo];

    __syncthreads();

    // ---- X (registers) -> hi/lo swizzled LDS for the PQ GEMM
#pragma unroll
    for (int rb = 0; rb < 4; ++rb)
#pragma unroll
        for (int r = 0; r < 4; ++r) {
            int row = rb * 16 + hi * 4 + r;
#pragma unroll
            for (int cb = 0; cb < 2; ++cb) {
                int col = colbase + cb * 16 + lo;
                float xv = acc2[rb][cb][r] + b2c[cb];
                unsigned short th = f2bf(xv);
                unsigned short tl = f2bf(xv - bf2f(th));
                int byte = row * 256 + ((col * 2) ^ ((row & 7) << 4));
                *(unsigned short*)((char*)s_h + byte) = th;
                *(unsigned short*)((char*)s_l + byte) = tl;
            }
        }
    __syncthreads();

    // ---- PQ GEMM for the next layer
    f32x4 accp[4][2], accq[4][2];
#pragma unroll
    for (int rb = 0; rb < 4; ++rb)
#pragma unroll
        for (int cb = 0; cb < 2; ++cb) {
            accp[rb][cb] = (f32x4){0.f, 0.f, 0.f, 0.f};
            accq[rb][cb] = (f32x4){0.f, 0.f, 0.f, 0.f};
        }

#pragma unroll
    for (int kc = 0; kc < 4; ++kc) {
        bf16x8 ah[4], al[4];
#pragma unroll
        for (int rb = 0; rb < 4; ++rb) {
            int row = rb * 16 + lo;
            int byte = row * 256 + ((kc * 64 + hi * 16) ^ ((row & 7) << 4));
            ah[rb] = *reinterpret_cast<const bf16x8*>((const char*)s_h + byte);
            al[rb] = *reinterpret_cast<const bf16x8*>((const char*)s_l + byte);
        }
#pragma unroll
        for (int cb = 0; cb < 2; ++cb) {
            size_t boff = ((size_t)((kc * 8 + w * 2 + cb) * 64 + lane)) * 8;
            bf16x8 bph = *reinterpret_cast<const bf16x8*>(pkpah + boff);
            bf16x8 bpl = *reinterpret_cast<const bf16x8*>(pkpal + boff);
            bf16x8 bqh = *reinterpret_cast<const bf16x8*>(pkqbh + boff);
            bf16x8 bql = *reinterpret_cast<const bf16x8*>(pkqbl + boff);
#pragma unroll
            for (int rb = 0; rb < 4; ++rb) {
                accp[rb][cb] = __builtin_amdgcn_mfma_f32_16x16x32_bf16(ah[rb], bph, accp[rb][cb], 0, 0, 0);
                accp[rb][cb] = __builtin_amdgcn_mfma_f32_16x16x32_bf16(al[rb], bph, accp[rb][cb], 0, 0, 0);
                accp[rb][cb] = __builtin_amdgcn_mfma_f32_16x16x32_bf16(ah[rb], bpl, accp[rb][cb], 0, 0, 0);
                accq[rb][cb] = __builtin_amdgcn_mfma_f32_16x16x32_bf16(ah[rb], bqh, accq[rb][cb], 0, 0, 0);
                accq[rb][cb] = __builtin_amdgcn_mfma_f32_16x16x32_bf16(al[rb], bqh, accq[rb][cb], 0, 0, 0);
                accq[rb][cb] = __builtin_amdgcn_mfma_f32_16x16x32_bf16(ah[rb], bql, accq[rb][cb], 0, 0, 0);
            }
        }
    }

#pragma unroll
    for (int rb = 0; rb < 4; ++rb)
#pragma unroll
        for (int r = 0; r < 4; ++r) {
            int row = r0 + rb * 16 + hi * 4 + r;
            if (row < NN) {
#pragma unroll
                for (int cb = 0; cb < 2; ++cb) {
                    int col = colbase + cb * 16 + lo;
                    P[(size_t)row * 128 + col] = accp[rb][cb][r];
                    Q[(size_t)row * 128 + col] = accq[rb][cb][r];
                }
            }
        }
}

// ---------------------------------------------------------------------------
// MFMA node update (last layer only): X_out = silu(agg@Wu1+b1)@Wu2+b2
// ---------------------------------------------------------------------------
__global__ __launch_bounds__(256, 2)
void nodeupd_kernel(const float* __restrict__ AGG,
                    const unsigned short* __restrict__ pku1h,
                    const unsigned short* __restrict__ pku1l,
                    const float* __restrict__ bu1,
                    const unsigned short* __restrict__ pku2h,
                    const unsigned short* __restrict__ pku2l,
                    const float* __restrict__ bu2,
                    float* __restrict__ Xout)
{
    __shared__ unsigned short s_h[64 * 128];  // 16 KB, swizzled (hi)
    __shared__ unsigned short s_l[64 * 128];  // 16 KB, swizzled (lo)

    const int tid = threadIdx.x;
    const int w = tid >> 6;
    const int lane = tid & 63;
    const int lo = lane & 15, hi = lane >> 4;
    const int r0 = blockIdx.x * 64;
    const int colbase = w * 32;

    for (int i = tid; i < 1024; i += 256) {
        int e = i >> 4, cg = i & 15;
        int r = r0 + e;
        union { unsigned short u16[8]; f4 v; } H, L;
        if (r < NN) {
            f4 v0 = ((const f4*)AGG)[(size_t)r * 32 + cg * 2];
            f4 v1 = ((const f4*)AGG)[(size_t)r * 32 + cg * 2 + 1];
#pragma unroll
            for (int q = 0; q < 4; ++q) {
                unsigned short h0 = f2bf(v0[q]);
                unsigned short h1 = f2bf(v1[q]);
                H.u16[q] = h0;     L.u16[q] = f2bf(v0[q] - bf2f(h0));
                H.u16[4 + q] = h1; L.u16[4 + q] = f2bf(v1[q] - bf2f(h1));
            }
        } else {
#pragma unroll
            for (int q = 0; q < 8; ++q) { H.u16[q] = 0; L.u16[q] = 0; }
        }
        int byte = e * 256 + ((cg * 16) ^ ((e & 7) << 4));
        *reinterpret_cast<f4*>((char*)s_h + byte) = H.v;
        *reinterpret_cast<f4*>((char*)s_l + byte) = L.v;
    }
    __syncthreads();

    // ---- stage 1: t = silu(agg @ Wu1 + b1)
    f32x4 acc[4][2];
#pragma unroll
    for (int rb = 0; rb < 4; ++rb)
#pragma unroll
        for (int cb = 0; cb < 2; ++cb) acc[rb][cb] = (f32x4){0.f, 0.f, 0.f, 0.f};

#pragma unroll
    for (int kc = 0; kc < 4; ++kc) {
        bf16x8 ah[4], al[4];
#pragma unroll
        for (int rb = 0; rb < 4; ++rb) {
            int row = rb * 16 + lo;
            int byte = row * 256 + ((kc * 64 + hi * 16) ^ ((row & 7) << 4));
            ah[rb] = *reinterpret_cast<const bf16x8*>((const char*)s_h + byte);
            al[rb] = *reinterpret_cast<const bf16x8*>((const char*)s_l + byte);
        }
#pragma unroll
        for (int cb = 0; cb < 2; ++cb) {
            size_t boff = ((size_t)((kc * 8 + w * 2 + cb) * 64 + lane)) * 8;
            bf16x8 bh = *reinterpret_cast<const bf16x8*>(pku1h + boff);
            bf16x8 bl = *reinterpret_cast<const bf16x8*>(pku1l + boff);
#pragma unroll
            for (int rb = 0; rb < 4; ++rb) {
                acc[rb][cb] = __builtin_amdgcn_mfma_f32_16x16x32_bf16(ah[rb], bh, acc[rb][cb], 0, 0, 0);
                acc[rb][cb] = __builtin_amdgcn_mfma_f32_16x16x32_bf16(al[rb], bh, acc[rb][cb], 0, 0, 0);
                acc[rb][cb] = __builtin_amdgcn_mfma_f32_16x16x32_bf16(ah[rb], bl, acc[rb][cb], 0, 0, 0);
            }
        }
    }

    float b1c[2];
#pragma unroll
    for (int cb = 0; cb < 2; ++cb) b1c[cb] = bu1[colbase + cb * 16 + lo];

    __syncthreads();

#pragma unroll
    for (int rb = 0; rb < 4; ++rb)
#pragma unroll
        for (int r = 0; r < 4; ++r) {
            int row = rb * 16 + hi * 4 + r;
#pragma unroll
            for (int cb = 0; cb < 2; ++cb) {
                int col = colbase + cb * 16 + lo;
                float t = silu1(acc[rb][cb][r] + b1c[cb]);
                unsigned short th = f2bf(t);
                unsigned short tl = f2bf(t - bf2f(th));
                int byte = row * 256 + ((col * 2) ^ ((row & 7) << 4));
                *(unsigned short*)((char*)s_h + byte) = th;
                *(unsigned short*)((char*)s_l + byte) = tl;
            }
        }
    __syncthreads();

    // ---- stage 2: X_out = t @ Wu2 + b2
    f32x4 acc2[4][2];
#pragma unroll
    for (int rb = 0; rb < 4; ++rb)
#pragma unroll
        for (int cb = 0; cb < 2; ++cb) acc2[rb][cb] = (f32x4){0.f, 0.f, 0.f, 0.f};

#pragma unroll
    for (int kc = 0; kc < 4; ++kc) {
        bf16x8 ah[4], al[4];
#pragma unroll
        for (int rb = 0; rb < 4; ++rb) {
            int row = rb * 16 + lo;
            int byte = row * 256 + ((kc * 64 + hi * 16) ^ ((row & 7) << 4));
            ah[rb] = *reinterpret_cast<const bf16x8*>((const char*)s_h + byte);
            al[rb] = *reinterpret_cast<const bf16x8*>((const char*)s_l + byte);
        }
#pragma unroll
        for (int cb = 0; cb < 2; ++cb) {
            size_t boff = ((size_t)((kc * 8 + w * 2 + cb) * 64 + lane)) * 8;
            bf16x8 bh = *reinterpret_cast<const bf16x8*>(pku2h + boff);
            bf16x8 bl = *reinterpret_cast<const bf16x8*>(pku2l + boff);
#pragma unroll
            for (int rb = 0; rb < 4; ++rb) {
                acc2[rb][cb] = __builtin_amdgcn_mfma_f32_16x16x32_bf16(ah[rb], bh, acc2[rb][cb], 0, 0, 0);
                acc2[rb][cb] = __builtin_amdgcn_mfma_f32_16x16x32_bf16(al[rb], bh, acc2[rb][cb], 0, 0, 0);
                acc2[rb][cb] = __builtin_amdgcn_mfma_f32_16x16x32_bf16(ah[rb], bl, acc2[rb][cb], 0, 0, 0);
            }
        }
    }

    float b2c[2];
#pragma unroll
    for (int cb = 0; cb < 2; ++cb) b2c[cb] = bu2[colbase + cb * 16 + lo];

#pragma unroll
    for (int rb = 0; rb < 4; ++rb)
#pragma unroll
        for (int r = 0; r < 4; ++r) {
            int row = r0 + rb * 16 + hi * 4 + r;
            if (row < NN) {
#pragma unroll
                for (int cb = 0; cb < 2; ++cb) {
                    int col = colbase + cb * 16 + lo;
                    Xout[(size_t)row * 128 + col] = acc2[rb][cb][r] + b2c[cb];
                }
            }
        }
}

// ---------------------------------------------------------------------------
// Graph readout: grid (G, 4); block reduces 32 cols of one graph segment
// ---------------------------------------------------------------------------
__global__ void gsum2_kernel(const float* __restrict__ X, const int* __restrict__ gstart,
                             float* __restrict__ Gm)
{
    __shared__ f4 red[32][8];
    int g = blockIdx.x;
    int q = blockIdx.y;
    int cq = threadIdx.x & 7;
    int cf = q * 8 + cq;          // f4 col (0..31)
    int rg = threadIdx.x >> 3;    // 0..31
    int i0 = gstart[g], i1 = gstart[g + 1];
    f4 s = {0.f, 0.f, 0.f, 0.f};
    for (int i = i0 + rg; i < i1; i += 32)
        s += ((const f4*)X)[(size_t)i * 32 + cf];
    red[rg][cq] = s;
    __syncthreads();
    for (int off = 16; off >= 1; off >>= 1) {
        if (rg < off) red[rg][cq] += red[rg + off][cq];
        __syncthreads();
    }
    if (rg == 0) ((f4*)Gm)[g * 32 + cf] = red[0][cq];
}

__global__ void final_kernel(const float* __restrict__ Gm,
                             const float* __restrict__ Wf1, const float* __restrict__ bf1,
                             const float* __restrict__ Wf2, const float* __restrict__ bf2,
                             float* __restrict__ out)
{
    __shared__ float red[128];
    int g = blockIdx.x;
    int j = threadIdx.x;
    float s = bf1[j];
    for (int k = 0; k < 128; ++k) s += Gm[(size_t)g * 128 + k] * Wf1[k * 128 + j];
    s = silu1(s);
    red[j] = s * Wf2[j];
    __syncthreads();
    for (int off = 64; off > 0; off >>= 1) {
        if (j < off) red[j] += red[j + off];
        __syncthreads();
    }
    if (j == 0) out[g] = red[0] + bf2[0];
}

// ---------------------------------------------------------------------------
extern "C" void kernel_launch(void* const* d_in, const int* in_sizes, int n_in,
                              void* d_out, int out_size, void* d_ws, size_t ws_size,
                              hipStream_t stream)
{
    const float* x     = (const float*)d_in[0];
    const float* pos   = (const float*)d_in[1];
    const int*   eidx  = (const int*)d_in[2];
    const int*   batch = (const int*)d_in[3];
    const float* Wnode = (const float*)d_in[4];
    const float* bnode = (const float*)d_in[5];
    const float* Wrbf  = (const float*)d_in[6];
    const float* brbf  = (const float*)d_in[7];
    const float* We1   = (const float*)d_in[8];
    const float* be1   = (const float*)d_in[9];
    const float* We2   = (const float*)d_in[10];
    const float* be2   = (const float*)d_in[11];
    const float* Wu1   = (const float*)d_in[12];
    const float* bu1   = (const float*)d_in[13];
    const float* Wu2   = (const float*)d_in[14];
    const float* bu2   = (const float*)d_in[15];
    const float* Wf1   = (const float*)d_in[16];
    const float* bf1   = (const float*)d_in[17];
    const float* Wf2   = (const float*)d_in[18];
    const float* bf2   = (const float*)d_in[19];

    const int* erow = eidx;
    const int* ecol = eidx + NE;

    char* wsb = (char*)d_ws;
    size_t off = 0;
    auto take = [&](size_t bytes) -> char* {
        char* p = wsb + off;
        off += (bytes + 255) & ~(size_t)255;
        return p;
    };
    float* Pb    = (float*)take((size_t)NN * HH * 4);
    float* Qb    = (float*)take((size_t)NN * HH * 4);
    float* aggb  = (float*)take((size_t)NN * HH * 4);
    float* xa    = (float*)take((size_t)NN * DD * 4);
    float* gm    = (float*)take((size_t)GG * DD * 4);
    float* Wpa   = (float*)take((size_t)LL * DD * HH * 4);
    float* Wqb   = (float*)take((size_t)LL * DD * HH * 4);
    float* Wcc   = (float*)take((size_t)LL * RR * HH * 4);
    float* bmsg  = (float*)take((size_t)LL * HH * 4);
    int*   cnt   = (int*)take((size_t)NN * 4);
    int*   cur   = (int*)take((size_t)NN * 4);
    int*   srow  = (int*)take((size_t)NE * 4);
    int*   scol  = (int*)take((size_t)NE * 4);
    float* sdist = (float*)take((size_t)NE * 4);
    int*   gst   = (int*)take((size_t)(GG + 1) * 4);
    unsigned short* pk1   = (unsigned short*)take((size_t)LL * RR * HH * 2);
    unsigned short* pk3   = (unsigned short*)take((size_t)LL * HH * HH * 2);
    unsigned short* pkpah = (unsigned short*)take((size_t)LL * DD * HH * 2);
    unsigned short* pkpal = (unsigned short*)take((size_t)LL * DD * HH * 2);
    unsigned short* pkqbh = (unsigned short*)take((size_t)LL * DD * HH * 2);
    unsigned short* pkqbl = (unsigned short*)take((size_t)LL * DD * HH * 2);
    unsigned short* pku1h = (unsigned short*)take((size_t)LL * HH * HH * 2);
    unsigned short* pku1l = (unsigned short*)take((size_t)LL * HH * HH * 2);
    unsigned short* pku2h = (unsigned short*)take((size_t)LL * HH * DD * 2);
    unsigned short* pku2l = (unsigned short*)take((size_t)LL * HH * DD * 2);

    if (off > ws_size) return;  // fail loudly (absmax), not a fault

    // ---- one-time preprocessing
    fillz_kernel<<<(NN + 1023) / 1024, 256, 0, stream>>>((float*)cnt, NN / 4);
    hist_kernel<<<(NE + 255) / 256, 256, 0, stream>>>(ecol, cnt);
    scan_kernel<<<1, 1024, 0, stream>>>(cnt, cur);
    scatter_kernel<<<(NE + 255) / 256, 256, 0, stream>>>(pos, erow, ecol, cur, srow, scol, sdist);
    gstart_kernel<<<(NN + 255) / 256, 256, 0, stream>>>(batch, gst);

    dim3 foldgrid((41088 + 255) / 256, LL);
    fold_kernel<<<foldgrid, 256, 0, stream>>>(Wnode, Wrbf, We1, bnode, brbf, be1,
                                              Wpa, Wqb, Wcc, bmsg);
    dim3 packgrid((90112 + 255) / 256, LL);
    packall_kernel<<<packgrid, 256, 0, stream>>>(Wcc, We2, Wpa, Wqb, Wu1, Wu2,
                                                 pk1, pk3, pkpah, pkpal, pkqbh, pkqbl,
                                                 pku1h, pku1l, pku2h, pku2l);

    // ---- layers (fused node path: X never round-trips through HBM)
    const int nblk = (NN + 63) / 64;
    nodepq_kernel<<<nblk, 256, 0, stream>>>(x, pkpah, pkpal, pkqbh, pkqbl,
                                            Pb, Qb, aggb);
    for (int l = 0; l < LL; ++l) {
        edge_mfma_kernel<<<NE / EB, 256, 0, stream>>>(Pb, Qb, sdist, srow, scol,
                                                      pk1 + (size_t)l * RR * HH,
                                                      pk3 + (size_t)l * HH * HH,
                                                      bmsg + (size_t)l * HH,
                                                      be2 + (size_t)l * HH, aggb);
        if (l < LL - 1) {
            nodefuse_kernel<<<nblk, 256, 0, stream>>>(
                aggb,
                pku1h + (size_t)l * HH * HH, pku1l + (size_t)l * HH * HH,
                bu1 + (size_t)l * HH,
                pku2h + (size_t)l * HH * DD, pku2l + (size_t)l * HH * DD,
                bu2 + (size_t)l * DD,
                pkpah + (size_t)(l + 1) * DD * HH, pkpal + (size_t)(l + 1) * DD * HH,
                pkqbh + (size_t)(l + 1) * DD * HH, pkqbl + (size_t)(l + 1) * DD * HH,
                Pb, Qb, aggb);
        } else {
            nodeupd_kernel<<<nblk, 256, 0, stream>>>(
                aggb,
                pku1h + (size_t)l * HH * HH, pku1l + (size_t)l * HH * HH,
                bu1 + (size_t)l * HH,
                pku2h + (size_t)l * HH * DD, pku2l + (size_t)l * HH * DD,
                bu2 + (size_t)l * DD, xa);
        }
    }

    dim3 gsgrid(GG, 4);
    gsum2_kernel<<<gsgrid, 256, 0, stream>>>(xa, gst, gm);
    final_kernel<<<GG, 128, 0, stream>>>(gm, Wf1, bf1, Wf2, bf2, (float*)d_out);
}

// Round 17
// 854.264 us; speedup vs baseline: 1.0810x; 1.0038x over previous
//
#include <hip/hip_runtime.h>
#include <hip/hip_bf16.h>

#define NN 50000   // nodes
#define NE 800000  // edges
#define DD 128     // node dim
#define HH 128     // hidden dim
#define RR 64      // num rbf
#define LL 4       // layers
#define GG 64      // graphs
#define EB 64      // edges per block (edge kernel)
#define NXCD 8     // XCDs on MI355X

typedef float f4 __attribute__((ext_vector_type(4)));
typedef __attribute__((ext_vector_type(8))) short bf16x8;  // MFMA A/B frag (4 VGPR)
typedef __attribute__((ext_vector_type(4))) float f32x4;   // MFMA C/D frag

// silu via hardware rcp (~1 ulp; way below bf16 quantum).
__device__ __forceinline__ float silu1(float v)
{
    return v * __builtin_amdgcn_rcpf(1.0f + __expf(-v));
}

// RNE float -> bf16 bits (branchless; inputs finite)
__device__ __forceinline__ unsigned short f2bf(float f)
{
    union { float f; unsigned u; } x; x.f = f;
    unsigned r = x.u + 0x7fffu + ((x.u >> 16) & 1u);
    return (unsigned short)(r >> 16);
}
__device__ __forceinline__ float bf2f(unsigned short h)
{
    union { unsigned u; float f; } x; x.u = ((unsigned)h) << 16; return x.f;
}
// Packed RNE pair convert via the official HIP API
__device__ __forceinline__ unsigned pk2bf(float a, float b)
{
    __hip_bfloat162 h = __float22bfloat162_rn(float2{a, b});
    union { __hip_bfloat162 h; unsigned u; } c; c.h = h;
    return c.u;
}

// ---------------------------------------------------------------------------
// Zero fill
// ---------------------------------------------------------------------------
__global__ void fillz_kernel(float* __restrict__ p, int n4)
{
    int i = blockIdx.x * 256 + threadIdx.x;
    if (i < n4) ((f4*)p)[i] = (f4){0.f, 0.f, 0.f, 0.f};
}

// ---------------------------------------------------------------------------
// Counting sort of edges by col (destination). One-time per call.
// ---------------------------------------------------------------------------
__global__ void hist_kernel(const int* __restrict__ ecol, int* __restrict__ cnt)
{
    int e = blockIdx.x * 256 + threadIdx.x;
    if (e < NE) atomicAdd(&cnt[ecol[e]], 1);
}

__global__ void scan_kernel(const int* __restrict__ cnt, int* __restrict__ cur)
{
    __shared__ int s[1024];
    int t = threadIdx.x;               // 1024 threads, 1 block
    const int CH = 49;                 // 1024*49 = 50176 >= NN
    int a0 = t * CH, a1 = a0 + CH; if (a1 > NN) a1 = NN; if (a0 > NN) a0 = NN;
    int s0 = 0;
    for (int i = a0; i < a1; ++i) s0 += cnt[i];
    s[t] = s0;
    __syncthreads();
    for (int off = 1; off < 1024; off <<= 1) {
        int v = (t >= off) ? s[t - off] : 0;
        __syncthreads();
        s[t] += v;
        __syncthreads();
    }
    int base = (t == 0) ? 0 : s[t - 1];
    for (int i = a0; i < a1; ++i) { cur[i] = base; base += cnt[i]; }
}

__global__ void scatter_kernel(const float* __restrict__ pos,
                               const int* __restrict__ erow, const int* __restrict__ ecol,
                               int* __restrict__ cur,
                               int* __restrict__ srow, int* __restrict__ scol,
                               float* __restrict__ sdist)
{
    int e = blockIdx.x * 256 + threadIdx.x;
    if (e >= NE) return;
    int r = erow[e], c = ecol[e];
    int p = atomicAdd(&cur[c], 1);
    srow[p] = r;
    scol[p] = c;
    float dx = pos[r * 3 + 0] - pos[c * 3 + 0];
    float dy = pos[r * 3 + 1] - pos[c * 3 + 1];
    float dz = pos[r * 3 + 2] - pos[c * 3 + 2];
    sdist[p] = sqrtf(dx * dx + dy * dy + dz * dz);
}

// ---------------------------------------------------------------------------
// Graph segment boundaries from sorted batch
// ---------------------------------------------------------------------------
__global__ void gstart_kernel(const int* __restrict__ batch, int* __restrict__ gstart)
{
    int i = blockIdx.x * 256 + threadIdx.x;
    if (i >= NN) return;
    int b = batch[i];
    if (i == 0) {
        for (int g = 0; g <= b; ++g) gstart[g] = 0;
    } else {
        int bp = batch[i - 1];
        for (int g = bp + 1; g <= b; ++g) gstart[g] = i;
    }
    if (i == NN - 1) {
        for (int g = b + 1; g <= GG; ++g) gstart[g] = NN;
    }
}

// ---------------------------------------------------------------------------
// Weight folding (fp32), parallel: one thread per output element.
// ---------------------------------------------------------------------------
__global__ void fold_kernel(const float* __restrict__ Wnode, const float* __restrict__ Wrbf,
                            const float* __restrict__ We1,
                            const float* __restrict__ bnode, const float* __restrict__ brbf,
                            const float* __restrict__ be1,
                            float* __restrict__ Wpa, float* __restrict__ Wqb,
                            float* __restrict__ Wc, float* __restrict__ bmsg)
{
    int l = blockIdx.y;
    int o = blockIdx.x * 256 + threadIdx.x;
    const float* We1l = We1 + (size_t)l * 384 * 128;
    if (o < 16384) {
        int r = o >> 7, c = o & 127;
        const float* A = Wnode + (size_t)l * 16384;
        float s = 0.f;
        for (int k = 0; k < 128; ++k) s += A[r * 128 + k] * We1l[k * 128 + c];
        Wpa[(size_t)l * 16384 + o] = s;
    } else if (o < 32768) {
        int oo = o - 16384;
        int r = oo >> 7, c = oo & 127;
        const float* A = Wnode + (size_t)l * 16384;
        const float* B = We1l + 16384;
        float s = 0.f;
        for (int k = 0; k < 128; ++k) s += A[r * 128 + k] * B[k * 128 + c];
        Wqb[(size_t)l * 16384 + oo] = s;
    } else if (o < 40960) {
        int oo = o - 32768;
        int r = oo >> 7, c = oo & 127;
        const float* A = Wrbf + (size_t)l * 8192;
        const float* B = We1l + 32768;
        float s = 0.f;
        for (int k = 0; k < 128; ++k) s += A[r * 128 + k] * B[k * 128 + c];
        Wc[(size_t)l * 8192 + oo] = s;
    } else if (o < 41088) {
        int j = o - 40960;
        float s = be1[l * 128 + j];
        for (int k = 0; k < 128; ++k) {
            float w = We1l[k * 128 + j] + We1l[(128 + k) * 128 + j];
            s += bnode[l * 128 + k] * w + brbf[l * 128 + k] * We1l[(256 + k) * 128 + j];
        }
        bmsg[l * 128 + j] = s;
    }
}

// ---------------------------------------------------------------------------
// Merged pack kernel: all 6 weight packings for one layer in one launch.
// ---------------------------------------------------------------------------
__global__ void packall_kernel(const float* __restrict__ Wcc, const float* __restrict__ We2,
                               const float* __restrict__ Wpa, const float* __restrict__ Wqb,
                               const float* __restrict__ Wu1, const float* __restrict__ Wu2,
                               unsigned short* __restrict__ pk1, unsigned short* __restrict__ pk3,
                               unsigned short* __restrict__ pkpah, unsigned short* __restrict__ pkpal,
                               unsigned short* __restrict__ pkqbh, unsigned short* __restrict__ pkqbl,
                               unsigned short* __restrict__ pku1h, unsigned short* __restrict__ pku1l,
                               unsigned short* __restrict__ pku2h, unsigned short* __restrict__ pku2l)
{
    int l = blockIdx.y;
    int g = blockIdx.x * 256 + threadIdx.x;
    if (g >= 90112) return;

    const float* src;
    unsigned short* dsth;
    unsigned short* dstl = nullptr;  // null -> single-precision pack
    int idx;
    if (g < 8192) {
        idx = g;            src = Wcc + (size_t)l * 8192;  dsth = pk1 + (size_t)l * 8192;
    } else if (g < 24576) {
        idx = g - 8192;     src = We2 + (size_t)l * 16384; dsth = pk3 + (size_t)l * 16384;
    } else if (g < 40960) {
        idx = g - 24576;    src = Wpa + (size_t)l * 16384;
        dsth = pkpah + (size_t)l * 16384; dstl = pkpal + (size_t)l * 16384;
    } else if (g < 57344) {
        idx = g - 40960;    src = Wqb + (size_t)l * 16384;
        dsth = pkqbh + (size_t)l * 16384; dstl = pkqbl + (size_t)l * 16384;
    } else if (g < 73728) {
        idx = g - 57344;    src = Wu1 + (size_t)l * 16384;
        dsth = pku1h + (size_t)l * 16384; dstl = pku1l + (size_t)l * 16384;
    } else {
        idx = g - 73728;    src = Wu2 + (size_t)l * 16384;
        dsth = pku2h + (size_t)l * 16384; dstl = pku2l + (size_t)l * 16384;
    }

    int k = idx >> 7, c = idx & 127;
    int kc = k >> 5, hi = (k >> 3) & 3, j = k & 7;
    int cbG = c >> 4, lo = c & 15;
    int lane = hi * 16 + lo;
    int o = (((kc * 8 + cbG) * 64 + lane) * 8) + j;
    float v = src[idx];
    unsigned short h = f2bf(v);
    dsth[o] = h;
    if (dstl) dstl[o] = f2bf(v - bf2f(h));
}

// ---------------------------------------------------------------------------
// MFMA dual node GEMM (first layer only): P = X @ Wpa, Q = X @ Wqb; zeroes agg.
// ---------------------------------------------------------------------------
__global__ __launch_bounds__(256, 2)
void nodepq_kernel(const float* __restrict__ X,
                   const unsigned short* __restrict__ pkpah,
                   const unsigned short* __restrict__ pkpal,
                   const unsigned short* __restrict__ pkqbh,
                   const unsigned short* __restrict__ pkqbl,
                   float* __restrict__ P, float* __restrict__ Q,
                   float* __restrict__ agg)
{
    __shared__ unsigned short s_h[64 * 128];  // 16 KB, swizzled (hi)
    __shared__ unsigned short s_l[64 * 128];  // 16 KB, swizzled (lo)

    const int tid = threadIdx.x;
    const int w = tid >> 6;
    const int lane = tid & 63;
    const int lo = lane & 15, hi = lane >> 4;
    const int r0 = blockIdx.x * 64;
    const int colbase = w * 32;

    for (int i = tid; i < 1024; i += 256) {
        int e = i >> 4, cg = i & 15;
        int r = r0 + e;
        union { unsigned short u16[8]; f4 v; } H, L;
        if (r < NN) {
            f4 v0 = ((const f4*)X)[(size_t)r * 32 + cg * 2];
            f4 v1 = ((const f4*)X)[(size_t)r * 32 + cg * 2 + 1];
#pragma unroll
            for (int q = 0; q < 4; ++q) {
                unsigned short h0 = f2bf(v0[q]);
                unsigned short h1 = f2bf(v1[q]);
                H.u16[q] = h0;     L.u16[q] = f2bf(v0[q] - bf2f(h0));
                H.u16[4 + q] = h1; L.u16[4 + q] = f2bf(v1[q] - bf2f(h1));
            }
        } else {
#pragma unroll
            for (int q = 0; q < 8; ++q) { H.u16[q] = 0; L.u16[q] = 0; }
        }
        int byte = e * 256 + ((cg * 16) ^ ((e & 7) << 4));
        *reinterpret_cast<f4*>((char*)s_h + byte) = H.v;
        *reinterpret_cast<f4*>((char*)s_l + byte) = L.v;
    }
    for (int i = tid; i < 2048; i += 256) {
        int e = i >> 5, cc = i & 31;
        int r = r0 + e;
        if (r < NN) ((f4*)agg)[(size_t)r * 32 + cc] = (f4){0.f, 0.f, 0.f, 0.f};
    }
    __syncthreads();

    f32x4 accp[4][2], accq[4][2];
#pragma unroll
    for (int rb = 0; rb < 4; ++rb)
#pragma unroll
        for (int cb = 0; cb < 2; ++cb) {
            accp[rb][cb] = (f32x4){0.f, 0.f, 0.f, 0.f};
            accq[rb][cb] = (f32x4){0.f, 0.f, 0.f, 0.f};
        }

#pragma unroll
    for (int kc = 0; kc < 4; ++kc) {
        bf16x8 ah[4], al[4];
#pragma unroll
        for (int rb = 0; rb < 4; ++rb) {
            int row = rb * 16 + lo;
            int byte = row * 256 + ((kc * 64 + hi * 16) ^ ((row & 7) << 4));
            ah[rb] = *reinterpret_cast<const bf16x8*>((const char*)s_h + byte);
            al[rb] = *reinterpret_cast<const bf16x8*>((const char*)s_l + byte);
        }
#pragma unroll
        for (int cb = 0; cb < 2; ++cb) {
            size_t boff = ((size_t)((kc * 8 + w * 2 + cb) * 64 + lane)) * 8;
            bf16x8 bph = *reinterpret_cast<const bf16x8*>(pkpah + boff);
            bf16x8 bpl = *reinterpret_cast<const bf16x8*>(pkpal + boff);
            bf16x8 bqh = *reinterpret_cast<const bf16x8*>(pkqbh + boff);
            bf16x8 bql = *reinterpret_cast<const bf16x8*>(pkqbl + boff);
#pragma unroll
            for (int rb = 0; rb < 4; ++rb) {
                accp[rb][cb] = __builtin_amdgcn_mfma_f32_16x16x32_bf16(ah[rb], bph, accp[rb][cb], 0, 0, 0);
                accp[rb][cb] = __builtin_amdgcn_mfma_f32_16x16x32_bf16(al[rb], bph, accp[rb][cb], 0, 0, 0);
                accp[rb][cb] = __builtin_amdgcn_mfma_f32_16x16x32_bf16(ah[rb], bpl, accp[rb][cb], 0, 0, 0);
                accq[rb][cb] = __builtin_amdgcn_mfma_f32_16x16x32_bf16(ah[rb], bqh, accq[rb][cb], 0, 0, 0);
                accq[rb][cb] = __builtin_amdgcn_mfma_f32_16x16x32_bf16(al[rb], bqh, accq[rb][cb], 0, 0, 0);
                accq[rb][cb] = __builtin_amdgcn_mfma_f32_16x16x32_bf16(ah[rb], bql, accq[rb][cb], 0, 0, 0);
            }
        }
    }

#pragma unroll
    for (int rb = 0; rb < 4; ++rb)
#pragma unroll
        for (int r = 0; r < 4; ++r) {
            int row = r0 + rb * 16 + hi * 4 + r;
            if (row < NN) {
#pragma unroll
                for (int cb = 0; cb < 2; ++cb) {
                    int col = colbase + cb * 16 + lo;
                    P[(size_t)row * 128 + col] = accp[rb][cb][r];
                    Q[(size_t)row * 128 + col] = accq[rb][cb][r];
                }
            }
        }
}

// ---------------------------------------------------------------------------
// MFMA edge kernel; round 17: bijective XCD-aware block swizzle (T1/m204)
// so each XCD's private L2 sees a contiguous edge range -> P[col] gather and
// agg atomics localize to ~3.2MB/XCD (fits 4MB L2). Pure reorder, no numerics.
// ---------------------------------------------------------------------------
__global__ __launch_bounds__(256, 4)
void edge_mfma_kernel(const float* __restrict__ P, const float* __restrict__ Q,
                      const float* __restrict__ sdist,
                      const int* __restrict__ srow, const int* __restrict__ scol,
                      const unsigned short* __restrict__ pk1,  // [2][8][64][8]
                      const unsigned short* __restrict__ pk3,  // [4][8][64][8]
                      const float* __restrict__ bmsg, const float* __restrict__ be2,
                      float* __restrict__ agg)
{
    __shared__ unsigned short s_t[EB * 128];  // 16 KB, swizzled (C1 then t, in place)
    __shared__ float s_d[EB];
    __shared__ int s_row[EB], s_col[EB];
    __shared__ int s_rs[EB + 1];
    __shared__ int s_nr;

    const int tid = threadIdx.x;
    const int w = tid >> 6;
    const int lane = tid & 63;
    const int lo = lane & 15, hi = lane >> 4;

    // XCD-aware bijective block swizzle (nwg % 8 != 0 safe; m204 formula)
    const int nwg = gridDim.x;
    const int q = nwg >> 3, r8 = nwg & 7;
    const int xcd = blockIdx.x & 7, bidx = blockIdx.x >> 3;
    const int bid = (xcd < r8 ? xcd * (q + 1) : r8 * (q + 1) + (xcd - r8) * q) + bidx;
    const int e0 = bid * EB;
    const int ew = w * 16;                    // wave's edge window [ew, ew+16)

    if (tid < EB) {
        s_d[tid] = sdist[e0 + tid];
        s_row[tid] = srow[e0 + tid];
        s_col[tid] = scol[e0 + tid];
    }
    __syncthreads();

    if (w == 0) {
        int c = s_col[lane];
        bool flag = (lane == 0) || (c != s_col[lane - 1]);
        unsigned long long m = __ballot(flag);
        if (flag) {
            int rank = __popcll(m & ((1ull << lane) - 1ull));
            s_rs[rank] = lane;
        }
        if (lane == 0) {
            int nr = __popcll(m);
            s_nr = nr;
            s_rs[nr] = EB;
        }
    }

    // ---- phase 1: C1 = RBF @ Wc  (K = 64); A row = local edge = lo
    f32x4 acc[8];
#pragma unroll
    for (int cb = 0; cb < 8; ++cb) acc[cb] = (f32x4){0.f, 0.f, 0.f, 0.f};

    const float dvv = s_d[ew + lo];
    const float step = 6.0f / 63.0f;
#pragma unroll
    for (int kc = 0; kc < 2; ++kc) {
        union { bf16x8 v; unsigned u32[4]; } U;
#pragma unroll
        for (int j2 = 0; j2 < 4; ++j2) {
            float t0 = dvv - (float)(kc * 32 + hi * 8 + 2 * j2) * step;
            float t1 = dvv - (float)(kc * 32 + hi * 8 + 2 * j2 + 1) * step;
            U.u32[j2] = pk2bf(__expf(-10.0f * t0 * t0), __expf(-10.0f * t1 * t1));
        }
#pragma unroll
        for (int cb = 0; cb < 8; ++cb) {
            bf16x8 b = *reinterpret_cast<const bf16x8*>(
                pk1 + ((size_t)((kc * 8 + cb) * 64 + lane)) * 8);
            acc[cb] = __builtin_amdgcn_mfma_f32_16x16x32_bf16(U.v, b, acc[cb], 0, 0, 0);
        }
    }

    // ---- phase 2a: dump C1 (bf16, packed converts) into s_t at final slots
#pragma unroll
    for (int r = 0; r < 4; ++r) {
        int e = ew + hi * 4 + r;
        int sw = (e & 7) << 4;
#pragma unroll
        for (int cb = 0; cb < 8; cb += 2) {
            unsigned pk = pk2bf(acc[cb][r], acc[cb + 1][r]);
            int c0 = cb * 16 + lo, c1 = c0 + 16;
            *(unsigned short*)((char*)s_t + e * 256 + ((c0 * 2) ^ sw)) = (unsigned short)pk;
            *(unsigned short*)((char*)s_t + e * 256 + ((c1 * 2) ^ sw)) = (unsigned short)(pk >> 16);
        }
    }
    __syncthreads();

    // ---- phase 2b: coalesced f4 gather of P,Q; v = C1+P+Q+bm; t = silu(v)
    {
        const int f4c = tid & 31;           // f4-col (cols 4*f4c .. 4*f4c+3)
        const int ebase = (tid >> 5) * 8;   // 8 edges per 32-thread group
        f4 bmv = ((const f4*)bmsg)[f4c];
#pragma unroll
        for (int p = 0; p < 8; ++p) {
            int e = ebase + p;
            int nc = s_col[e], nr = s_row[e];
            f4 pv = ((const f4*)(P + (size_t)nc * 128))[f4c];
            f4 qv = ((const f4*)(Q + (size_t)nr * 128))[f4c];
            int byte = e * 256 + ((f4c * 8) ^ ((e & 7) << 4));
            unsigned long long c1 = *(unsigned long long*)((char*)s_t + byte);
            float t[4];
#pragma unroll
            for (int j = 0; j < 4; ++j) {
                float c1f = bf2f((unsigned short)(c1 >> (16 * j)));
                t[j] = silu1(c1f + pv[j] + qv[j] + bmv[j]);
            }
            unsigned lo32 = pk2bf(t[0], t[1]);
            unsigned hi32 = pk2bf(t[2], t[3]);
            *(unsigned long long*)((char*)s_t + byte) =
                (unsigned long long)lo32 | ((unsigned long long)hi32 << 32);
        }
    }
    __syncthreads();

    // ---- phase 3: M = T @ We2  (K = 128); A row = ew + lo
    f32x4 acc2[8];
#pragma unroll
    for (int cb = 0; cb < 8; ++cb) acc2[cb] = (f32x4){0.f, 0.f, 0.f, 0.f};

    {
        const int rowA = ew + lo;
        const int swA = (rowA & 7) << 4;
#pragma unroll
        for (int kc = 0; kc < 4; ++kc) {
            bf16x8 a = *reinterpret_cast<const bf16x8*>(
                (const char*)s_t + rowA * 256 + ((kc * 64 + hi * 16) ^ swA));
#pragma unroll
            for (int cb = 0; cb < 8; ++cb) {
                bf16x8 b = *reinterpret_cast<const bf16x8*>(
                    pk3 + ((size_t)((kc * 8 + cb) * 64 + lane)) * 8);
                acc2[cb] = __builtin_amdgcn_mfma_f32_16x16x32_bf16(a, b, acc2[cb], 0, 0, 0);
            }
        }
    }

    // ---- phase 4: per-run reduce clipped to this wave's window + atomicAdd
    float be2c[8];
#pragma unroll
    for (int cb = 0; cb < 8; ++cb) be2c[cb] = be2[cb * 16 + lo];

    int nruns = s_nr;
    for (int ri = 0; ri < nruns; ++ri) {
        int a0 = s_rs[ri], b0 = s_rs[ri + 1];
        if (b0 <= ew || a0 >= ew + 16) continue;   // wave-uniform skip
        int la = a0 - ew; if (la < 0) la = 0;
        int lb = b0 - ew; if (lb > 16) lb = 16;
        int node = s_col[a0];
        float s[8];
#pragma unroll
        for (int cb = 0; cb < 8; ++cb) s[cb] = 0.f;
#pragma unroll
        for (int r = 0; r < 4; ++r) {
            int el = hi * 4 + r;
            bool in = (el >= la) && (el < lb);
#pragma unroll
            for (int cb = 0; cb < 8; ++cb)
                s[cb] += in ? acc2[cb][r] : 0.f;
        }
#pragma unroll
        for (int cb = 0; cb < 8; ++cb) {
            s[cb] += __shfl_xor(s[cb], 16, 64);
            s[cb] += __shfl_xor(s[cb], 32, 64);
        }
        if (hi == 0) {
            float len = (float)(lb - la);
            float* dst = agg + (size_t)node * 128;
#pragma unroll
            for (int cb = 0; cb < 8; ++cb)
                atomicAdd(dst + cb * 16 + lo, s[cb] + len * be2c[cb]);
        }
    }
}

// ---------------------------------------------------------------------------
// FUSED node kernel (layer boundaries): X in registers; P,Q for next layer.
// ---------------------------------------------------------------------------
__global__ __launch_bounds__(256, 2)
void nodefuse_kernel(const float* __restrict__ AGG,
                     const unsigned short* __restrict__ pku1h,
                     const unsigned short* __restrict__ pku1l,
                     const float* __restrict__ bu1,
                     const unsigned short* __restrict__ pku2h,
                     const unsigned short* __restrict__ pku2l,
                     const float* __restrict__ bu2,
                     const unsigned short* __restrict__ pkpah,
                     const unsigned short* __restrict__ pkpal,
                     const unsigned short* __restrict__ pkqbh,
                     const unsigned short* __restrict__ pkqbl,
                     float* __restrict__ P, float* __restrict__ Q,
                     float* __restrict__ agg)
{
    __shared__ unsigned short s_h[64 * 128];  // 16 KB, swizzled (hi)
    __shared__ unsigned short s_l[64 * 128];  // 16 KB, swizzled (lo)

    const int tid = threadIdx.x;
    const int w = tid >> 6;
    const int lane = tid & 63;
    const int lo = lane & 15, hi = lane >> 4;
    const int r0 = blockIdx.x * 64;
    const int colbase = w * 32;

    for (int i = tid; i < 1024; i += 256) {
        int e = i >> 4, cg = i & 15;
        int r = r0 + e;
        union { unsigned short u16[8]; f4 v; } H, L;
        if (r < NN) {
            f4 v0 = ((const f4*)AGG)[(size_t)r * 32 + cg * 2];
            f4 v1 = ((const f4*)AGG)[(size_t)r * 32 + cg * 2 + 1];
#pragma unroll
            for (int q = 0; q < 4; ++q) {
                unsigned short h0 = f2bf(v0[q]);
                unsigned short h1 = f2bf(v1[q]);
                H.u16[q] = h0;     L.u16[q] = f2bf(v0[q] - bf2f(h0));
                H.u16[4 + q] = h1; L.u16[4 + q] = f2bf(v1[q] - bf2f(h1));
            }
        } else {
#pragma unroll
            for (int q = 0; q < 8; ++q) { H.u16[q] = 0; L.u16[q] = 0; }
        }
        int byte = e * 256 + ((cg * 16) ^ ((e & 7) << 4));
        *reinterpret_cast<f4*>((char*)s_h + byte) = H.v;
        *reinterpret_cast<f4*>((char*)s_l + byte) = L.v;
    }
    __syncthreads();

    // re-zero agg rows for the next layer
    for (int i = tid; i < 2048; i += 256) {
        int e = i >> 5, cc = i & 31;
        int r = r0 + e;
        if (r < NN) ((f4*)agg)[(size_t)r * 32 + cc] = (f4){0.f, 0.f, 0.f, 0.f};
    }

    // ---- stage 1: t = silu(agg @ Wu1 + b1)
    f32x4 acc[4][2];
#pragma unroll
    for (int rb = 0; rb < 4; ++rb)
#pragma unroll
        for (int cb = 0; cb < 2; ++cb) acc[rb][cb] = (f32x4){0.f, 0.f, 0.f, 0.f};

#pragma unroll
    for (int kc = 0; kc < 4; ++kc) {
        bf16x8 ah[4], al[4];
#pragma unroll
        for (int rb = 0; rb < 4; ++rb) {
            int row = rb * 16 + lo;
            int byte = row * 256 + ((kc * 64 + hi * 16) ^ ((row & 7) << 4));
            ah[rb] = *reinterpret_cast<const bf16x8*>((const char*)s_h + byte);
            al[rb] = *reinterpret_cast<const bf16x8*>((const char*)s_l + byte);
        }
#pragma unroll
        for (int cb = 0; cb < 2; ++cb) {
            size_t boff = ((size_t)((kc * 8 + w * 2 + cb) * 64 + lane)) * 8;
            bf16x8 bh = *reinterpret_cast<const bf16x8*>(pku1h + boff);
            bf16x8 bl = *reinterpret_cast<const bf16x8*>(pku1l + boff);
#pragma unroll
            for (int rb = 0; rb < 4; ++rb) {
                acc[rb][cb] = __builtin_amdgcn_mfma_f32_16x16x32_bf16(ah[rb], bh, acc[rb][cb], 0, 0, 0);
                acc[rb][cb] = __builtin_amdgcn_mfma_f32_16x16x32_bf16(al[rb], bh, acc[rb][cb], 0, 0, 0);
                acc[rb][cb] = __builtin_amdgcn_mfma_f32_16x16x32_bf16(ah[rb], bl, acc[rb][cb], 0, 0, 0);
            }
        }
    }

    float b1c[2];
#pragma unroll
    for (int cb = 0; cb < 2; ++cb) b1c[cb] = bu1[colbase + cb * 16 + lo];

    __syncthreads();

#pragma unroll
    for (int rb = 0; rb < 4; ++rb)
#pragma unroll
        for (int r = 0; r < 4; ++r) {
            int row = rb * 16 + hi * 4 + r;
#pragma unroll
            for (int cb = 0; cb < 2; ++cb) {
                int col = colbase + cb * 16 + lo;
                float t = silu1(acc[rb][cb][r] + b1c[cb]);
                unsigned short th = f2bf(t);
                unsigned short tl = f2bf(t - bf2f(th));
                int byte = row * 256 + ((col * 2) ^ ((row & 7) << 4));
                *(unsigned short*)((char*)s_h + byte) = th;
                *(unsigned short*)((char*)s_l + byte) = tl;
            }
        }
    __syncthreads();

    // ---- stage 2: X = t @ Wu2 + b2 (kept in registers)
    f32x4 acc2[4][2];
#pragma unroll
    for (int rb = 0; rb < 4; ++rb)
#pragma unroll
        for (int cb = 0; cb < 2; ++cb) acc2[rb][cb] = (f32x4){0.f, 0.f, 0.f, 0.f};

#pragma unroll
    for (int kc = 0; kc < 4; ++kc) {
        bf16x8 ah[4], al[4];
#pragma unroll
        for (int rb = 0; rb < 4; ++rb) {
            int row = rb * 16 + lo;
            int byte = row * 256 + ((kc * 64 + hi * 16) ^ ((row & 7) << 4));
            ah[rb] = *reinterpret_cast<const bf16x8*>((const char*)s_h + byte);
            al[rb] = *reinterpret_cast<const bf16x8*>((const char*)s_l + byte);
        }
#pragma unroll
        for (int cb = 0; cb < 2; ++cb) {
            size_t boff = ((size_t)((kc * 8 + w * 2 + cb) * 64 + lane)) * 8;
            bf16x8 bh = *reinterpret_cast<const bf16x8*>(pku2h + boff);
            bf16x8 bl = *reinterpret_cast<const bf16x8*>(pku2l + boff);
#pragma unroll
            for (int rb = 0; rb < 4; ++rb) {
                acc2[rb][cb] = __builtin_amdgcn_mfma_f32_16x16x32_bf16(ah[rb], bh, acc2[rb][cb], 0, 0, 0);
                acc2[rb][cb] = __builtin_amdgcn_mfma_f32_16x16x32_bf16(al[rb], bh, acc2[rb][cb], 0, 0, 0);
                acc2[rb][cb] = __builtin_amdgcn_mfma_f32_16x16x32_bf16(ah[rb], bl, acc2[rb][cb], 0, 0, 0);
            }
        }
    }

    float b2c[2];
#pragma unroll
    for (int cb = 0; cb < 2; ++cb) b2c[cb] = bu2[colbase + cb * 16 + lo];

    __syncthreads();

    // ---- X (registers) -> hi/lo swizzled LDS for the PQ GEMM
#pragma unroll
    for (int rb = 0; rb < 4; ++rb)
#pragma unroll
        for (int r = 0; r < 4; ++r) {
            int row = rb * 16 + hi * 4 + r;
#pragma unroll
            for (int cb = 0; cb < 2; ++cb) {
                int col = colbase + cb * 16 + lo;
                float xv = acc2[rb][cb][r] + b2c[cb];
                unsigned short th = f2bf(xv);
                unsigned short tl = f2bf(xv - bf2f(th));
                int byte = row * 256 + ((col * 2) ^ ((row & 7) << 4));
                *(unsigned short*)((char*)s_h + byte) = th;
                *(unsigned short*)((char*)s_l + byte) = tl;
            }
        }
    __syncthreads();

    // ---- PQ GEMM for the next layer
    f32x4 accp[4][2], accq[4][2];
#pragma unroll
    for (int rb = 0; rb < 4; ++rb)
#pragma unroll
        for (int cb = 0; cb < 2; ++cb) {
            accp[rb][cb] = (f32x4){0.f, 0.f, 0.f, 0.f};
            accq[rb][cb] = (f32x4){0.f, 0.f, 0.f, 0.f};
        }

#pragma unroll
    for (int kc = 0; kc < 4; ++kc) {
        bf16x8 ah[4], al[4];
#pragma unroll
        for (int rb = 0; rb < 4; ++rb) {
            int row = rb * 16 + lo;
            int byte = row * 256 + ((kc * 64 + hi * 16) ^ ((row & 7) << 4));
            ah[rb] = *reinterpret_cast<const bf16x8*>((const char*)s_h + byte);
            al[rb] = *reinterpret_cast<const bf16x8*>((const char*)s_l + byte);
        }
#pragma unroll
        for (int cb = 0; cb < 2; ++cb) {
            size_t boff = ((size_t)((kc * 8 + w * 2 + cb) * 64 + lane)) * 8;
            bf16x8 bph = *reinterpret_cast<const bf16x8*>(pkpah + boff);
            bf16x8 bpl = *reinterpret_cast<const bf16x8*>(pkpal + boff);
            bf16x8 bqh = *reinterpret_cast<const bf16x8*>(pkqbh + boff);
            bf16x8 bql = *reinterpret_cast<const bf16x8*>(pkqbl + boff);
#pragma unroll
            for (int rb = 0; rb < 4; ++rb) {
                accp[rb][cb] = __builtin_amdgcn_mfma_f32_16x16x32_bf16(ah[rb], bph, accp[rb][cb], 0, 0, 0);
                accp[rb][cb] = __builtin_amdgcn_mfma_f32_16x16x32_bf16(al[rb], bph, accp[rb][cb], 0, 0, 0);
                accp[rb][cb] = __builtin_amdgcn_mfma_f32_16x16x32_bf16(ah[rb], bpl, accp[rb][cb], 0, 0, 0);
                accq[rb][cb] = __builtin_amdgcn_mfma_f32_16x16x32_bf16(ah[rb], bqh, accq[rb][cb], 0, 0, 0);
                accq[rb][cb] = __builtin_amdgcn_mfma_f32_16x16x32_bf16(al[rb], bqh, accq[rb][cb], 0, 0, 0);
                accq[rb][cb] = __builtin_amdgcn_mfma_f32_16x16x32_bf16(ah[rb], bql, accq[rb][cb], 0, 0, 0);
            }
        }
    }

#pragma unroll
    for (int rb = 0; rb < 4; ++rb)
#pragma unroll
        for (int r = 0; r < 4; ++r) {
            int row = r0 + rb * 16 + hi * 4 + r;
            if (row < NN) {
#pragma unroll
                for (int cb = 0; cb < 2; ++cb) {
                    int col = colbase + cb * 16 + lo;
                    P[(size_t)row * 128 + col] = accp[rb][cb][r];
                    Q[(size_t)row * 128 + col] = accq[rb][cb][r];
                }
            }
        }
}

// ---------------------------------------------------------------------------
// MFMA node update (last layer only): X_out = silu(agg@Wu1+b1)@Wu2+b2
// ---------------------------------------------------------------------------
__global__ __launch_bounds__(256, 2)
void nodeupd_kernel(const float* __restrict__ AGG,
                    const unsigned short* __restrict__ pku1h,
                    const unsigned short* __restrict__ pku1l,
                    const float* __restrict__ bu1,
                    const unsigned short* __restrict__ pku2h,
                    const unsigned short* __restrict__ pku2l,
                    const float* __restrict__ bu2,
                    float* __restrict__ Xout)
{
    __shared__ unsigned short s_h[64 * 128];  // 16 KB, swizzled (hi)
    __shared__ unsigned short s_l[64 * 128];  // 16 KB, swizzled (lo)

    const int tid = threadIdx.x;
    const int w = tid >> 6;
    const int lane = tid & 63;
    const int lo = lane & 15, hi = lane >> 4;
    const int r0 = blockIdx.x * 64;
    const int colbase = w * 32;

    for (int i = tid; i < 1024; i += 256) {
        int e = i >> 4, cg = i & 15;
        int r = r0 + e;
        union { unsigned short u16[8]; f4 v; } H, L;
        if (r < NN) {
            f4 v0 = ((const f4*)AGG)[(size_t)r * 32 + cg * 2];
            f4 v1 = ((const f4*)AGG)[(size_t)r * 32 + cg * 2 + 1];
#pragma unroll
            for (int q = 0; q < 4; ++q) {
                unsigned short h0 = f2bf(v0[q]);
                unsigned short h1 = f2bf(v1[q]);
                H.u16[q] = h0;     L.u16[q] = f2bf(v0[q] - bf2f(h0));
                H.u16[4 + q] = h1; L.u16[4 + q] = f2bf(v1[q] - bf2f(h1));
            }
        } else {
#pragma unroll
            for (int q = 0; q < 8; ++q) { H.u16[q] = 0; L.u16[q] = 0; }
        }
        int byte = e * 256 + ((cg * 16) ^ ((e & 7) << 4));
        *reinterpret_cast<f4*>((char*)s_h + byte) = H.v;
        *reinterpret_cast<f4*>((char*)s_l + byte) = L.v;
    }
    __syncthreads();

    // ---- stage 1: t = silu(agg @ Wu1 + b1)
    f32x4 acc[4][2];
#pragma unroll
    for (int rb = 0; rb < 4; ++rb)
#pragma unroll
        for (int cb = 0; cb < 2; ++cb) acc[rb][cb] = (f32x4){0.f, 0.f, 0.f, 0.f};

#pragma unroll
    for (int kc = 0; kc < 4; ++kc) {
        bf16x8 ah[4], al[4];
#pragma unroll
        for (int rb = 0; rb < 4; ++rb) {
            int row = rb * 16 + lo;
            int byte = row * 256 + ((kc * 64 + hi * 16) ^ ((row & 7) << 4));
            ah[rb] = *reinterpret_cast<const bf16x8*>((const char*)s_h + byte);
            al[rb] = *reinterpret_cast<const bf16x8*>((const char*)s_l + byte);
        }
#pragma unroll
        for (int cb = 0; cb < 2; ++cb) {
            size_t boff = ((size_t)((kc * 8 + w * 2 + cb) * 64 + lane)) * 8;
            bf16x8 bh = *reinterpret_cast<const bf16x8*>(pku1h + boff);
            bf16x8 bl = *reinterpret_cast<const bf16x8*>(pku1l + boff);
#pragma unroll
            for (int rb = 0; rb < 4; ++rb) {
                acc[rb][cb] = __builtin_amdgcn_mfma_f32_16x16x32_bf16(ah[rb], bh, acc[rb][cb], 0, 0, 0);
                acc[rb][cb] = __builtin_amdgcn_mfma_f32_16x16x32_bf16(al[rb], bh, acc[rb][cb], 0, 0, 0);
                acc[rb][cb] = __builtin_amdgcn_mfma_f32_16x16x32_bf16(ah[rb], bl, acc[rb][cb], 0, 0, 0);
            }
        }
    }

    float b1c[2];
#pragma unroll
    for (int cb = 0; cb < 2; ++cb) b1c[cb] = bu1[colbase + cb * 16 + lo];

    __syncthreads();

#pragma unroll
    for (int rb = 0; rb < 4; ++rb)
#pragma unroll
        for (int r = 0; r < 4; ++r) {
            int row = rb * 16 + hi * 4 + r;
#pragma unroll
            for (int cb = 0; cb < 2; ++cb) {
                int col = colbase + cb * 16 + lo;
                float t = silu1(acc[rb][cb][r] + b1c[cb]);
                unsigned short th = f2bf(t);
                unsigned short tl = f2bf(t - bf2f(th));
                int byte = row * 256 + ((col * 2) ^ ((row & 7) << 4));
                *(unsigned short*)((char*)s_h + byte) = th;
                *(unsigned short*)((char*)s_l + byte) = tl;
            }
        }
    __syncthreads();

    // ---- stage 2: X_out = t @ Wu2 + b2
    f32x4 acc2[4][2];
#pragma unroll
    for (int rb = 0; rb < 4; ++rb)
#pragma unroll
        for (int cb = 0; cb < 2; ++cb) acc2[rb][cb] = (f32x4){0.f, 0.f, 0.f, 0.f};

#pragma unroll
    for (int kc = 0; kc < 4; ++kc) {
        bf16x8 ah[4], al[4];
#pragma unroll
        for (int rb = 0; rb < 4; ++rb) {
            int row = rb * 16 + lo;
            int byte = row * 256 + ((kc * 64 + hi * 16) ^ ((row & 7) << 4));
            ah[rb] = *reinterpret_cast<const bf16x8*>((const char*)s_h + byte);
            al[rb] = *reinterpret_cast<const bf16x8*>((const char*)s_l + byte);
        }
#pragma unroll
        for (int cb = 0; cb < 2; ++cb) {
            size_t boff = ((size_t)((kc * 8 + w * 2 + cb) * 64 + lane)) * 8;
            bf16x8 bh = *reinterpret_cast<const bf16x8*>(pku2h + boff);
            bf16x8 bl = *reinterpret_cast<const bf16x8*>(pku2l + boff);
#pragma unroll
            for (int rb = 0; rb < 4; ++rb) {
                acc2[rb][cb] = __builtin_amdgcn_mfma_f32_16x16x32_bf16(ah[rb], bh, acc2[rb][cb], 0, 0, 0);
                acc2[rb][cb] = __builtin_amdgcn_mfma_f32_16x16x32_bf16(al[rb], bh, acc2[rb][cb], 0, 0, 0);
                acc2[rb][cb] = __builtin_amdgcn_mfma_f32_16x16x32_bf16(ah[rb], bl, acc2[rb][cb], 0, 0, 0);
            }
        }
    }

    float b2c[2];
#pragma unroll
    for (int cb = 0; cb < 2; ++cb) b2c[cb] = bu2[colbase + cb * 16 + lo];

#pragma unroll
    for (int rb = 0; rb < 4; ++rb)
#pragma unroll
        for (int r = 0; r < 4; ++r) {
            int row = r0 + rb * 16 + hi * 4 + r;
            if (row < NN) {
#pragma unroll
                for (int cb = 0; cb < 2; ++cb) {
                    int col = colbase + cb * 16 + lo;
                    Xout[(size_t)row * 128 + col] = acc2[rb][cb][r] + b2c[cb];
                }
            }
        }
}

// ---------------------------------------------------------------------------
// Graph readout: grid (G, 4); block reduces 32 cols of one graph segment
// ---------------------------------------------------------------------------
__global__ void gsum2_kernel(const float* __restrict__ X, const int* __restrict__ gstart,
                             float* __restrict__ Gm)
{
    __shared__ f4 red[32][8];
    int g = blockIdx.x;
    int q = blockIdx.y;
    int cq = threadIdx.x & 7;
    int cf = q * 8 + cq;          // f4 col (0..31)
    int rg = threadIdx.x >> 3;    // 0..31
    int i0 = gstart[g], i1 = gstart[g + 1];
    f4 s = {0.f, 0.f, 0.f, 0.f};
    for (int i = i0 + rg; i < i1; i += 32)
        s += ((const f4*)X)[(size_t)i * 32 + cf];
    red[rg][cq] = s;
    __syncthreads();
    for (int off = 16; off >= 1; off >>= 1) {
        if (rg < off) red[rg][cq] += red[rg + off][cq];
        __syncthreads();
    }
    if (rg == 0) ((f4*)Gm)[g * 32 + cf] = red[0][cq];
}

__global__ void final_kernel(const float* __restrict__ Gm,
                             const float* __restrict__ Wf1, const float* __restrict__ bf1,
                             const float* __restrict__ Wf2, const float* __restrict__ bf2,
                             float* __restrict__ out)
{
    __shared__ float red[128];
    int g = blockIdx.x;
    int j = threadIdx.x;
    float s = bf1[j];
    for (int k = 0; k < 128; ++k) s += Gm[(size_t)g * 128 + k] * Wf1[k * 128 + j];
    s = silu1(s);
    red[j] = s * Wf2[j];
    __syncthreads();
    for (int off = 64; off > 0; off >>= 1) {
        if (j < off) red[j] += red[j + off];
        __syncthreads();
    }
    if (j == 0) out[g] = red[0] + bf2[0];
}

// ---------------------------------------------------------------------------
extern "C" void kernel_launch(void* const* d_in, const int* in_sizes, int n_in,
                              void* d_out, int out_size, void* d_ws, size_t ws_size,
                              hipStream_t stream)
{
    const float* x     = (const float*)d_in[0];
    const float* pos   = (const float*)d_in[1];
    const int*   eidx  = (const int*)d_in[2];
    const int*   batch = (const int*)d_in[3];
    const float* Wnode = (const float*)d_in[4];
    const float* bnode = (const float*)d_in[5];
    const float* Wrbf  = (const float*)d_in[6];
    const float* brbf  = (const float*)d_in[7];
    const float* We1   = (const float*)d_in[8];
    const float* be1   = (const float*)d_in[9];
    const float* We2   = (const float*)d_in[10];
    const float* be2   = (const float*)d_in[11];
    const float* Wu1   = (const float*)d_in[12];
    const float* bu1   = (const float*)d_in[13];
    const float* Wu2   = (const float*)d_in[14];
    const float* bu2   = (const float*)d_in[15];
    const float* Wf1   = (const float*)d_in[16];
    const float* bf1   = (const float*)d_in[17];
    const float* Wf2   = (const float*)d_in[18];
    const float* bf2   = (const float*)d_in[19];

    const int* erow = eidx;
    const int* ecol = eidx + NE;

    char* wsb = (char*)d_ws;
    size_t off = 0;
    auto take = [&](size_t bytes) -> char* {
        char* p = wsb + off;
        off += (bytes + 255) & ~(size_t)255;
        return p;
    };
    float* Pb    = (float*)take((size_t)NN * HH * 4);
    float* Qb    = (float*)take((size_t)NN * HH * 4);
    float* aggb  = (float*)take((size_t)NN * HH * 4);
    float* xa    = (float*)take((size_t)NN * DD * 4);
    float* gm    = (float*)take((size_t)GG * DD * 4);
    float* Wpa   = (float*)take((size_t)LL * DD * HH * 4);
    float* Wqb   = (float*)take((size_t)LL * DD * HH * 4);
    float* Wcc   = (float*)take((size_t)LL * RR * HH * 4);
    float* bmsg  = (float*)take((size_t)LL * HH * 4);
    int*   cnt   = (int*)take((size_t)NN * 4);
    int*   cur   = (int*)take((size_t)NN * 4);
    int*   srow  = (int*)take((size_t)NE * 4);
    int*   scol  = (int*)take((size_t)NE * 4);
    float* sdist = (float*)take((size_t)NE * 4);
    int*   gst   = (int*)take((size_t)(GG + 1) * 4);
    unsigned short* pk1   = (unsigned short*)take((size_t)LL * RR * HH * 2);
    unsigned short* pk3   = (unsigned short*)take((size_t)LL * HH * HH * 2);
    unsigned short* pkpah = (unsigned short*)take((size_t)LL * DD * HH * 2);
    unsigned short* pkpal = (unsigned short*)take((size_t)LL * DD * HH * 2);
    unsigned short* pkqbh = (unsigned short*)take((size_t)LL * DD * HH * 2);
    unsigned short* pkqbl = (unsigned short*)take((size_t)LL * DD * HH * 2);
    unsigned short* pku1h = (unsigned short*)take((size_t)LL * HH * HH * 2);
    unsigned short* pku1l = (unsigned short*)take((size_t)LL * HH * HH * 2);
    unsigned short* pku2h = (unsigned short*)take((size_t)LL * HH * DD * 2);
    unsigned short* pku2l = (unsigned short*)take((size_t)LL * HH * DD * 2);

    if (off > ws_size) return;  // fail loudly (absmax), not a fault

    // ---- one-time preprocessing
    fillz_kernel<<<(NN + 1023) / 1024, 256, 0, stream>>>((float*)cnt, NN / 4);
    hist_kernel<<<(NE + 255) / 256, 256, 0, stream>>>(ecol, cnt);
    scan_kernel<<<1, 1024, 0, stream>>>(cnt, cur);
    scatter_kernel<<<(NE + 255) / 256, 256, 0, stream>>>(pos, erow, ecol, cur, srow, scol, sdist);
    gstart_kernel<<<(NN + 255) / 256, 256, 0, stream>>>(batch, gst);

    dim3 foldgrid((41088 + 255) / 256, LL);
    fold_kernel<<<foldgrid, 256, 0, stream>>>(Wnode, Wrbf, We1, bnode, brbf, be1,
                                              Wpa, Wqb, Wcc, bmsg);
    dim3 packgrid((90112 + 255) / 256, LL);
    packall_kernel<<<packgrid, 256, 0, stream>>>(Wcc, We2, Wpa, Wqb, Wu1, Wu2,
                                                 pk1, pk3, pkpah, pkpal, pkqbh, pkqbl,
                                                 pku1h, pku1l, pku2h, pku2l);

    // ---- layers (fused node path: X never round-trips through HBM)
    const int nblk = (NN + 63) / 64;
    nodepq_kernel<<<nblk, 256, 0, stream>>>(x, pkpah, pkpal, pkqbh, pkqbl,
                                            Pb, Qb, aggb);
    for (int l = 0; l < LL; ++l) {
        edge_mfma_kernel<<<NE / EB, 256, 0, stream>>>(Pb, Qb, sdist, srow, scol,
                                                      pk1 + (size_t)l * RR * HH,
                                                      pk3 + (size_t)l * HH * HH,
                                                      bmsg + (size_t)l * HH,
                                                      be2 + (size_t)l * HH, aggb);
        if (l < LL - 1) {
            nodefuse_kernel<<<nblk, 256, 0, stream>>>(
                aggb,
                pku1h + (size_t)l * HH * HH, pku1l + (size_t)l * HH * HH,
                bu1 + (size_t)l * HH,
                pku2h + (size_t)l * HH * DD, pku2l + (size_t)l * HH * DD,
                bu2 + (size_t)l * DD,
                pkpah + (size_t)(l + 1) * DD * HH, pkpal + (size_t)(l + 1) * DD * HH,
                pkqbh + (size_t)(l + 1) * DD * HH, pkqbl + (size_t)(l + 1) * DD * HH,
                Pb, Qb, aggb);
        } else {
            nodeupd_kernel<<<nblk, 256, 0, stream>>>(
                aggb,
                pku1h + (size_t)l * HH * HH, pku1l + (size_t)l * HH * HH,
                bu1 + (size_t)l * HH,
                pku2h + (size_t)l * HH * DD, pku2l + (size_t)l * HH * DD,
                bu2 + (size_t)l * DD, xa);
        }
    }

    dim3 gsgrid(GG, 4);
    gsum2_kernel<<<gsgrid, 256, 0, stream>>>(xa, gst, gm);
    final_kernel<<<GG, 128, 0, stream>>>(gm, Wf1, bf1, Wf2, bf2, (float*)d_out);
}